// Round 1
// baseline (9636.173 us; speedup 1.0000x reference)
//
#include <hip/hip_runtime.h>
#include <math.h>

#define DEV __device__ __forceinline__

// ---------------------------------------------------------------------------
// Block-wide reduction (256 threads = 4 waves of 64). mode 0 = sum, 1 = max.
// ---------------------------------------------------------------------------
DEV float block_reduce(float v, int mode) {
    #pragma unroll
    for (int off = 32; off; off >>= 1) {
        float o = __shfl_xor(v, off);
        v = mode ? fmaxf(v, o) : (v + o);
    }
    __shared__ float sbuf[4];
    __syncthreads();                       // protect sbuf from previous use
    if ((threadIdx.x & 63) == 0) sbuf[threadIdx.x >> 6] = v;
    __syncthreads();
    float r = sbuf[0];
    #pragma unroll
    for (int w = 1; w < 4; w++) r = mode ? fmaxf(r, sbuf[w]) : (r + sbuf[w]);
    return r;
}

DEV float softplus_f(float x) {            // log(1 + e^x), stable
    return fmaxf(x, 0.f) + log1pf(expf(-fabsf(x)));
}

// ---------------------------------------------------------------------------
// Generic fp32 GEMM: C[M,N] = A[M,K] @ W[K,N] (+bias) (+=C if ACCUM)
// 64x64 tile, BK=16, 256 threads, 4x4 per thread. All dims % 64 == 0 here.
// ---------------------------------------------------------------------------
template <bool ADD_BIAS, bool ACCUM>
__global__ __launch_bounds__(256) void gemm_kernel(
    const float* __restrict__ A, const float* __restrict__ W,
    const float* __restrict__ bias, float* __restrict__ C, int K, int N)
{
    __shared__ float As[16][64];   // As[k][m] (transposed A tile)
    __shared__ float Bs[16][64];   // Bs[k][n]
    const int tid = threadIdx.x;
    const int tn = tid & 15, tm = tid >> 4;
    const int m0 = blockIdx.y * 64, n0 = blockIdx.x * 64;

    float acc[4][4];
    #pragma unroll
    for (int i = 0; i < 4; i++)
        #pragma unroll
        for (int j = 0; j < 4; j++) acc[i][j] = 0.f;

    const int ar = tid >> 2, akc = (tid & 3) * 4;     // A tile load coords
    const int bkr = tid >> 4, bnc = (tid & 15) * 4;   // B tile load coords
    const float* Aptr = A + (size_t)(m0 + ar) * K + akc;
    const float* Wptr = W + (size_t)bkr * N + n0 + bnc;

    for (int k0 = 0; k0 < K; k0 += 16) {
        float4 av = *(const float4*)(Aptr + k0);
        As[akc + 0][ar] = av.x; As[akc + 1][ar] = av.y;
        As[akc + 2][ar] = av.z; As[akc + 3][ar] = av.w;
        *(float4*)&Bs[bkr][bnc] = *(const float4*)(Wptr + (size_t)k0 * N);
        __syncthreads();
        #pragma unroll
        for (int kk = 0; kk < 16; kk++) {
            float4 a4 = *(const float4*)&As[kk][tm * 4];
            float4 b4 = *(const float4*)&Bs[kk][tn * 4];
            float aa[4] = {a4.x, a4.y, a4.z, a4.w};
            float bb[4] = {b4.x, b4.y, b4.z, b4.w};
            #pragma unroll
            for (int i = 0; i < 4; i++)
                #pragma unroll
                for (int j = 0; j < 4; j++) acc[i][j] += aa[i] * bb[j];
        }
        __syncthreads();
    }

    float4 bias4 = make_float4(0.f, 0.f, 0.f, 0.f);
    if (ADD_BIAS) bias4 = *(const float4*)(bias + n0 + tn * 4);
    #pragma unroll
    for (int i = 0; i < 4; i++) {
        size_t off = (size_t)(m0 + tm * 4 + i) * N + n0 + tn * 4;
        float4 c;
        c.x = acc[i][0] + bias4.x; c.y = acc[i][1] + bias4.y;
        c.z = acc[i][2] + bias4.z; c.w = acc[i][3] + bias4.w;
        if (ACCUM) {
            float4 o = *(const float4*)(C + off);
            c.x += o.x; c.y += o.y; c.z += o.z; c.w += o.w;
        }
        *(float4*)(C + off) = c;
    }
}

// ---------------------------------------------------------------------------
// LayerNorm over 1024 cols; optional residuals r1, r2 added before LN.
// One block (256 thr, float4/thread) per row.
// ---------------------------------------------------------------------------
DEV void ln_finish(float4 xv, const float* __restrict__ g,
                   const float* __restrict__ bb, float* __restrict__ out,
                   size_t base)
{
    float s  = xv.x + xv.y + xv.z + xv.w;
    float s2 = xv.x * xv.x + xv.y * xv.y + xv.z * xv.z + xv.w * xv.w;
    #pragma unroll
    for (int off = 32; off; off >>= 1) {
        s += __shfl_xor(s, off);
        s2 += __shfl_xor(s2, off);
    }
    __shared__ float sa[4], sb[4];
    if ((threadIdx.x & 63) == 0) {
        sa[threadIdx.x >> 6] = s; sb[threadIdx.x >> 6] = s2;
    }
    __syncthreads();
    s  = sa[0] + sa[1] + sa[2] + sa[3];
    s2 = sb[0] + sb[1] + sb[2] + sb[3];
    const float mu  = s * (1.f / 1024.f);
    const float var = fmaxf(s2 * (1.f / 1024.f) - mu * mu, 0.f);
    const float inv = rsqrtf(var + 1e-12f);
    const int tid = threadIdx.x;
    float4 gv = ((const float4*)g)[tid];
    float4 bv = ((const float4*)bb)[tid];
    float4 o;
    o.x = (xv.x - mu) * inv * gv.x + bv.x;
    o.y = (xv.y - mu) * inv * gv.y + bv.y;
    o.z = (xv.z - mu) * inv * gv.z + bv.z;
    o.w = (xv.w - mu) * inv * gv.w + bv.w;
    ((float4*)(out + base))[tid] = o;
}

__global__ __launch_bounds__(256) void ln_kernel(
    const float* __restrict__ x, const float* __restrict__ r1,
    const float* __restrict__ r2, const float* __restrict__ g,
    const float* __restrict__ bb, float* __restrict__ out)
{
    const size_t base = (size_t)blockIdx.x * 1024;
    const int tid = threadIdx.x;
    float4 xv = ((const float4*)(x + base))[tid];
    if (r1) {
        float4 a = ((const float4*)(r1 + base))[tid];
        xv.x += a.x; xv.y += a.y; xv.z += a.z; xv.w += a.w;
    }
    if (r2) {
        float4 a = ((const float4*)(r2 + base))[tid];
        xv.x += a.x; xv.y += a.y; xv.z += a.z; xv.w += a.w;
    }
    ln_finish(xv, g, bb, out, base);
}

// cross_out = LN( sigmoid(gpre)*co + (1-sigmoid(gpre))*gn )
__global__ __launch_bounds__(256) void gate_ln_kernel(
    const float* __restrict__ gpre, const float* __restrict__ co,
    const float* __restrict__ gn, const float* __restrict__ g,
    const float* __restrict__ bb, float* __restrict__ out)
{
    const size_t base = (size_t)blockIdx.x * 1024;
    const int tid = threadIdx.x;
    float4 gp = ((const float4*)(gpre + base))[tid];
    float4 cv = ((const float4*)(co + base))[tid];
    float4 gv = ((const float4*)(gn + base))[tid];
    float4 xv; float s;
    s = 1.f / (1.f + expf(-gp.x)); xv.x = s * cv.x + (1.f - s) * gv.x;
    s = 1.f / (1.f + expf(-gp.y)); xv.y = s * cv.y + (1.f - s) * gv.y;
    s = 1.f / (1.f + expf(-gp.z)); xv.z = s * cv.z + (1.f - s) * gv.z;
    s = 1.f / (1.f + expf(-gp.w)); xv.w = s * cv.w + (1.f - s) * gv.w;
    ln_finish(xv, g, bb, out, base);
}

// exact GELU, in place, float4 per thread
__global__ __launch_bounds__(256) void gelu_kernel(float* __restrict__ x)
{
    const size_t i = (size_t)blockIdx.x * 256 + threadIdx.x;
    float4 v = ((float4*)x)[i];
    v.x = 0.5f * v.x * (1.f + erff(v.x * 0.70710678118654752f));
    v.y = 0.5f * v.y * (1.f + erff(v.y * 0.70710678118654752f));
    v.z = 0.5f * v.z * (1.f + erff(v.z * 0.70710678118654752f));
    v.w = 0.5f * v.w * (1.f + erff(v.w * 0.70710678118654752f));
    ((float4*)x)[i] = v;
}

// ---------------------------------------------------------------------------
// Main attention, one block per (b, h, n).  h==0: q1/k1 path (am0 mask).
// h in 1..3: struct heads — focal-loss partials on UNSCALED s+am0, softmax on
// s/16 + (1-smask)*-1e4.  ctx written in [B,N, h*256+d] layout.
// ---------------------------------------------------------------------------
__global__ __launch_bounds__(256) void attn_main_kernel(
    const float* __restrict__ qh, const float* __restrict__ kh,   // [B*N,768]
    const float* __restrict__ q1, const float* __restrict__ k1,   // [B*N,256]
    const float* __restrict__ v,                                  // [B*N,1024]
    const float* __restrict__ am,                                 // [B,N]
    const float* __restrict__ smask,                              // [B,3,N,N]
    float* __restrict__ ctx, float* __restrict__ nump, float* __restrict__ denp)
{
    const int n = blockIdx.x, h = blockIdx.y, b = blockIdx.z;
    const int tid = threadIdx.x;
    __shared__ __align__(16) float sq[256];
    __shared__ float sp[1024];
    const int bn = b * 1024 + n;

    const float* qrow; const float* kbase; int kstride;
    if (h == 0) {
        qrow = q1 + (size_t)bn * 256;
        kbase = k1 + (size_t)b * 1024 * 256; kstride = 256;
    } else {
        qrow = qh + (size_t)bn * 768 + (h - 1) * 256;
        kbase = kh + (size_t)b * 1024 * 768 + (h - 1) * 256; kstride = 768;
    }
    sq[tid] = qrow[tid];
    __syncthreads();

    // raw scores (4 per thread)
    float sraw[4];
    #pragma unroll
    for (int i = 0; i < 4; i++) {
        const int m = i * 256 + tid;
        const float4* kr4 = (const float4*)(kbase + (size_t)m * kstride);
        const float4* sq4 = (const float4*)sq;
        float acc = 0.f;
        #pragma unroll 8
        for (int d4 = 0; d4 < 64; d4++) {
            float4 kv = kr4[d4], qv = sq4[d4];
            acc += kv.x * qv.x + kv.y * qv.y + kv.z * qv.z + kv.w * qv.w;
        }
        sraw[i] = acc;
    }

    const float amn = am[bn];
    const float* smrow = (h > 0)
        ? smask + (((size_t)b * 3 + (h - 1)) * 1024 + n) * 1024 : nullptr;

    float sc[4], flsum = 0.f, dencnt = 0.f, lmax = -3.4e38f;
    #pragma unroll
    for (int i = 0; i < 4; i++) {
        const int m = i * 256 + tid;
        const float amm = am[b * 1024 + m];
        const float am0 = (1.f - amm) * (-10000.f);
        if (h > 0) {
            const float t  = smrow[m];
            const float s3 = sraw[i] + am0;
            const float idxw =
                ((amn * amm * ((m == n) ? 0.f : 1.f)) > 0.5f) ? 1.f : 0.f;
            const float p   = 1.f / (1.f + expf(-s3));
            const float spp = softplus_f(-s3);   // -log_sigmoid(s3)
            const float spn = softplus_f(s3);    // -log_sigmoid(-s3)
            const float fl  = 0.25f * t * (1.f - p) * (1.f - p) * spp
                            + 0.75f * (1.f - t) * p * p * spn;
            flsum += fl * idxw;
            if (h == 1) dencnt += idxw;
            sc[i] = sraw[i] * 0.0625f + (1.f - t) * (-10000.f);
        } else {
            sc[i] = sraw[i] * 0.0625f + am0;
        }
        lmax = fmaxf(lmax, sc[i]);
    }

    const float bmax = block_reduce(lmax, 1);
    float esum = 0.f;
    #pragma unroll
    for (int i = 0; i < 4; i++) {
        const float e = expf(sc[i] - bmax);
        sp[i * 256 + tid] = e;
        esum += e;
    }
    const float bsum = block_reduce(esum, 0);
    const float inv = 1.f / bsum;

    if (h > 0) {
        const float fb = block_reduce(flsum, 0);
        if (tid == 0) nump[((size_t)b * 3 + (h - 1)) * 1024 + n] = fb;
        if (h == 1) {
            const float db = block_reduce(dencnt, 0);
            if (tid == 0) denp[bn] = db;
        }
    }
    __syncthreads();

    // p @ V : thread = output dim d (coalesced v reads)
    float accv = 0.f;
    const float* vb = v + (size_t)b * 1048576 + h * 256 + tid;
    #pragma unroll 8
    for (int m = 0; m < 1024; m++) accv += sp[m] * vb[(size_t)m * 1024];
    ctx[(size_t)bn * 1024 + h * 256 + tid] = accv * inv;
}

// ---------------------------------------------------------------------------
// Cross attention, one block per (b, h, n). qk head dim 64, v head dim 256.
// ---------------------------------------------------------------------------
__global__ __launch_bounds__(256) void attn_cross_kernel(
    const float* __restrict__ cq,   // [B*N, 256] (4 x 64)
    const float* __restrict__ ck,   // [B*M, 256]
    const float* __restrict__ cv,   // [B*M, 1024] (4 x 256)
    const float* __restrict__ csm,  // [B,1,N,M]
    float* __restrict__ cctx)       // [B*N, 1024]
{
    const int n = blockIdx.x, h = blockIdx.y, b = blockIdx.z;
    const int tid = threadIdx.x;
    __shared__ __align__(16) float sq[64];
    __shared__ float sp[512];
    const int bn = b * 1024 + n;

    if (tid < 64) sq[tid] = cq[(size_t)bn * 256 + h * 64 + tid];
    __syncthreads();

    float sc[2], lmax = -3.4e38f;
    #pragma unroll
    for (int i = 0; i < 2; i++) {
        const int m = i * 256 + tid;
        const float4* kr4 = (const float4*)(ck + ((size_t)(b * 512 + m)) * 256 + h * 64);
        const float4* sq4 = (const float4*)sq;
        float acc = 0.f;
        #pragma unroll
        for (int d4 = 0; d4 < 16; d4++) {
            float4 kv = kr4[d4], qv = sq4[d4];
            acc += kv.x * qv.x + kv.y * qv.y + kv.z * qv.z + kv.w * qv.w;
        }
        const float msk = csm[((size_t)b * 1024 + n) * 512 + m];
        sc[i] = acc * 0.125f + (1.f - msk) * (-10000.f);
        lmax = fmaxf(lmax, sc[i]);
    }
    const float bmax = block_reduce(lmax, 1);
    float esum = 0.f;
    #pragma unroll
    for (int i = 0; i < 2; i++) {
        const float e = expf(sc[i] - bmax);
        sp[i * 256 + tid] = e;
        esum += e;
    }
    const float bsum = block_reduce(esum, 0);
    const float inv = 1.f / bsum;
    __syncthreads();

    float acc = 0.f;
    const float* vb = cv + (size_t)b * 512 * 1024 + h * 256 + tid;
    #pragma unroll 8
    for (int m = 0; m < 512; m++) acc += sp[m] * vb[(size_t)m * 1024];
    cctx[(size_t)bn * 1024 + h * 256 + tid] = acc * inv;
}

// ---------------------------------------------------------------------------
// Deterministic double-precision loss reduce: loss = sum(num)/(3*sum(den))
// ---------------------------------------------------------------------------
__global__ __launch_bounds__(256) void loss_reduce_kernel(
    const float* __restrict__ nump, const float* __restrict__ denp,
    float* __restrict__ out)
{
    __shared__ double sn[256], sd[256];
    const int tid = threadIdx.x;
    double ns = 0.0, ds = 0.0;
    for (int i = tid; i < 24576; i += 256) ns += (double)nump[i];
    for (int i = tid; i < 8192;  i += 256) ds += (double)denp[i];
    sn[tid] = ns; sd[tid] = ds;
    __syncthreads();
    for (int off = 128; off; off >>= 1) {
        if (tid < off) { sn[tid] += sn[tid + off]; sd[tid] += sd[tid + off]; }
        __syncthreads();
    }
    if (tid == 0) out[0] = (float)(sn[0] / (3.0 * sd[0]));
}

// ---------------------------------------------------------------------------
extern "C" void kernel_launch(void* const* d_in, const int* in_sizes, int n_in,
                              void* d_out, int out_size, void* d_ws, size_t ws_size,
                              hipStream_t stream)
{
    (void)in_sizes; (void)n_in; (void)out_size; (void)ws_size;
    const float* hs   = (const float*)d_in[0];
    const float* am   = (const float*)d_in[1];
    const float* smask= (const float*)d_in[2];
    const float* sent = (const float*)d_in[3];
    const float* ent  = (const float*)d_in[4];
    const float* csm  = (const float*)d_in[5];
    const float* enc  = (const float*)d_in[6];
    /* d_in[7] encoder_attention_mask: unused by reference */
    const float* Wq  = (const float*)d_in[8];  const float* bq  = (const float*)d_in[9];
    const float* Wk  = (const float*)d_in[10]; const float* bk  = (const float*)d_in[11];
    const float* Wv  = (const float*)d_in[12]; const float* bv  = (const float*)d_in[13];
    const float* Wq1 = (const float*)d_in[14]; const float* bq1 = (const float*)d_in[15];
    const float* Wk1 = (const float*)d_in[16]; const float* bk1 = (const float*)d_in[17];
    const float* ln_g= (const float*)d_in[18]; const float* ln_b= (const float*)d_in[19];
    const float* gW  = (const float*)d_in[20]; const float* gb  = (const float*)d_in[21];
    const float* gng = (const float*)d_in[22]; const float* gnb = (const float*)d_in[23];
    const float* cWq = (const float*)d_in[24]; const float* cbq = (const float*)d_in[25];
    const float* cWk = (const float*)d_in[26]; const float* cbk = (const float*)d_in[27];
    const float* cWv = (const float*)d_in[28]; const float* cbv = (const float*)d_in[29];
    const float* cWo = (const float*)d_in[30]; const float* cbo = (const float*)d_in[31];
    const float* cWg = (const float*)d_in[32]; const float* cbg = (const float*)d_in[33];
    const float* clg = (const float*)d_in[34]; const float* clb = (const float*)d_in[35];
    const float* oW1 = (const float*)d_in[36]; const float* ob1 = (const float*)d_in[37];
    const float* l1g = (const float*)d_in[38]; const float* l1b = (const float*)d_in[39];
    const float* oW2 = (const float*)d_in[40]; const float* ob2 = (const float*)d_in[41];
    const float* oW3 = (const float*)d_in[42]; const float* ob3 = (const float*)d_in[43];
    const float* l3g = (const float*)d_in[44]; const float* l3b = (const float*)d_in[45];
    float* out = (float*)d_out;

    // workspace slabs (floats). Peak usage 71,303,168 floats = 285 MB.
    float* ws = (float*)d_ws;
    const size_t SL = 8388608;                 // 8192*1024
    float* slabA = ws;                         // v        -> cq|ck|cv
    float* slabB = ws + SL;                    // h1       -> cctx -> h3
    float* slabC = ws + 2 * SL;                // q        -> cctx_o
    float* slabD = ws + 3 * SL;                // k        -> gate_pre
    float* slabE = ws + 4 * SL;                // q1 | k1   (4,194,304)
    float* slabF = ws + 4 * SL + 4194304;      // ctx      -> cross_out
    float* slabG = slabF + SL;                 // gnn_out  -> h
    float* slabI = slabG + SL;                 // partials / gemm tmp / h2 (16,777,216)

    dim3 blk(256);
    // ---- projections ----
    gemm_kernel<true,  false><<<dim3(12, 128), blk, 0, stream>>>(hs, Wq, bq, slabC, 1024, 768);
    gemm_kernel<true,  false><<<dim3(12, 128), blk, 0, stream>>>(hs, Wk, bk, slabD, 1024, 768);
    gemm_kernel<true,  false><<<dim3(16, 128), blk, 0, stream>>>(hs, Wv, bv, slabA, 1024, 1024);
    ln_kernel<<<8192, blk, 0, stream>>>(hs, sent, ent, ln_g, ln_b, slabB);       // h1
    gemm_kernel<true,  false><<<dim3(4, 128), blk, 0, stream>>>(slabB, Wq1, bq1, slabE, 1024, 256);
    gemm_kernel<true,  false><<<dim3(4, 128), blk, 0, stream>>>(slabB, Wk1, bk1, slabE + 2097152, 1024, 256);
    // ---- attention + focal loss ----
    attn_main_kernel<<<dim3(1024, 4, 8), blk, 0, stream>>>(
        slabC, slabD, slabE, slabE + 2097152, slabA, am, smask,
        slabF, slabI, slabI + 24576);
    loss_reduce_kernel<<<1, blk, 0, stream>>>(slabI, slabI + 24576, out + SL);
    // ---- gnn ----
    gemm_kernel<true,  false><<<dim3(16, 128), blk, 0, stream>>>(slabF, gW, gb, slabI, 1024, 1024);
    ln_kernel<<<8192, blk, 0, stream>>>(slabI, nullptr, nullptr, gng, gnb, slabG); // gnn_out
    // ---- cross attention ----
    gemm_kernel<true,  false><<<dim3(4, 128), blk, 0, stream>>>(slabG, cWq, cbq, slabA, 1024, 256);
    gemm_kernel<true,  false><<<dim3(4, 64),  blk, 0, stream>>>(enc, cWk, cbk, slabA + 2097152, 1024, 256);
    gemm_kernel<true,  false><<<dim3(16, 64), blk, 0, stream>>>(enc, cWv, cbv, slabA + 3145728, 1024, 1024);
    attn_cross_kernel<<<dim3(1024, 4, 8), blk, 0, stream>>>(
        slabA, slabA + 2097152, slabA + 3145728, csm, slabB);
    gemm_kernel<true,  false><<<dim3(16, 128), blk, 0, stream>>>(slabB, cWo, cbo, slabC, 1024, 1024);
    // ---- gate ----
    gemm_kernel<true,  false><<<dim3(16, 128), blk, 0, stream>>>(slabG, cWg, cbg, slabD, 1024, 1024);
    gemm_kernel<false, true ><<<dim3(16, 128), blk, 0, stream>>>(slabC, cWg + 1048576, nullptr, slabD, 1024, 1024);
    gate_ln_kernel<<<8192, blk, 0, stream>>>(slabD, slabC, slabG, clg, clb, slabF); // cross_out
    // ---- output block ----
    gemm_kernel<true,  false><<<dim3(16, 128), blk, 0, stream>>>(slabF, oW1, ob1, slabI, 1024, 1024);
    ln_kernel<<<8192, blk, 0, stream>>>(slabI, hs, nullptr, l1g, l1b, slabG);      // h
    gemm_kernel<true,  false><<<dim3(32, 128), blk, 0, stream>>>(slabG, oW2, ob2, slabI, 1024, 2048);
    gelu_kernel<<<16384, blk, 0, stream>>>(slabI);
    gemm_kernel<true,  false><<<dim3(16, 128), blk, 0, stream>>>(slabI, oW3, ob3, slabB, 2048, 1024);
    ln_kernel<<<8192, blk, 0, stream>>>(slabB, slabG, nullptr, l3g, l3b, out);     // out
}

// Round 2
// 2539.339 us; speedup vs baseline: 3.7948x; 3.7948x over previous
//
#include <hip/hip_runtime.h>
#include <math.h>

#define DEV __device__ __forceinline__

typedef short short8 __attribute__((ext_vector_type(8)));
typedef float float4v __attribute__((ext_vector_type(4)));

// round-to-nearest-even fp32 -> bf16 (values here are finite; no NaN path)
DEV unsigned short f2bf(float f) {
    union { float f; unsigned u; } v; v.f = f;
    unsigned r = v.u + 0x7FFFu + ((v.u >> 16) & 1u);
    return (unsigned short)(r >> 16);
}

DEV float softplus_f(float x) {            // log(1 + e^x), stable
    return fmaxf(x, 0.f) + log1pf(__expf(-fabsf(x)));
}

// block-wide reduction (256 threads). mode 0 = sum, 1 = max.
DEV float block_reduce(float v, int mode) {
    #pragma unroll
    for (int off = 32; off; off >>= 1) {
        float o = __shfl_xor(v, off);
        v = mode ? fmaxf(v, o) : (v + o);
    }
    __shared__ float sbuf[4];
    __syncthreads();
    if ((threadIdx.x & 63) == 0) sbuf[threadIdx.x >> 6] = v;
    __syncthreads();
    float r = sbuf[0];
    #pragma unroll
    for (int w = 1; w < 4; w++) r = mode ? fmaxf(r, sbuf[w]) : (r + sbuf[w]);
    return r;
}

// ---------------------------------------------------------------------------
// bf16 MFMA GEMM: C[M,N] = A[M,K] @ Wt[N,K]^T (+bias)(+=Cf)(GELU)
// 128x128 tile, BK=32, 256 thr = 4 waves (2x2 of 64x64), 4x4 MFMA tiles/wave.
// Writes fp32 (Cf) and/or bf16 (Cb) when non-null.
// ---------------------------------------------------------------------------
template <bool BIAS, bool ACCUM, bool GELU>
__global__ __launch_bounds__(256) void gemm_bf16_kernel(
    const unsigned short* __restrict__ A, int lda,
    const unsigned short* __restrict__ Bt, int ldb,
    const float* __restrict__ bias,
    float* __restrict__ Cf, unsigned short* __restrict__ Cb,
    int N, int K)
{
    __shared__ unsigned short As[128 * 40];   // [row][k] pitch 40 (pad 8)
    __shared__ unsigned short Bs[128 * 40];   // [n-row][k]
    const int tid = threadIdx.x;
    const int w = tid >> 6, lane = tid & 63;
    const int l15 = lane & 15, quad = lane >> 4;
    const int m0 = blockIdx.y * 128, n0 = blockIdx.x * 128;
    const int wm = (w >> 1) * 64, wn = (w & 1) * 64;

    float4v acc[4][4];
    #pragma unroll
    for (int i = 0; i < 4; i++)
        #pragma unroll
        for (int j = 0; j < 4; j++) acc[i][j] = (float4v){0.f, 0.f, 0.f, 0.f};

    for (int k0 = 0; k0 < K; k0 += 32) {
        __syncthreads();
        #pragma unroll
        for (int i = 0; i < 2; i++) {
            const int c = tid + i * 256;          // 512 chunks of 16B
            const int row = c >> 2, kc = (c & 3) * 8;
            *(uint4*)(As + row * 40 + kc) =
                *(const uint4*)(A + (size_t)(m0 + row) * lda + k0 + kc);
            *(uint4*)(Bs + row * 40 + kc) =
                *(const uint4*)(Bt + (size_t)(n0 + row) * ldb + k0 + kc);
        }
        __syncthreads();
        short8 Af[4], Bf[4];
        #pragma unroll
        for (int mt = 0; mt < 4; mt++)
            Af[mt] = *(const short8*)(As + (wm + mt * 16 + l15) * 40 + quad * 8);
        #pragma unroll
        for (int nt = 0; nt < 4; nt++)
            Bf[nt] = *(const short8*)(Bs + (wn + nt * 16 + l15) * 40 + quad * 8);
        #pragma unroll
        for (int mt = 0; mt < 4; mt++)
            #pragma unroll
            for (int nt = 0; nt < 4; nt++)
                acc[mt][nt] = __builtin_amdgcn_mfma_f32_16x16x32_bf16(
                    Af[mt], Bf[nt], acc[mt][nt], 0, 0, 0);
    }

    #pragma unroll
    for (int nt = 0; nt < 4; nt++) {
        const int n = n0 + wn + nt * 16 + l15;
        const float bv = BIAS ? bias[n] : 0.f;
        #pragma unroll
        for (int mt = 0; mt < 4; mt++) {
            #pragma unroll
            for (int r = 0; r < 4; r++) {
                const int m = m0 + wm + mt * 16 + quad * 4 + r;
                const size_t off = (size_t)m * N + n;
                float v = acc[mt][nt][r] + bv;
                if (ACCUM) v += Cf[off];
                if (GELU) v = 0.5f * v * (1.f + erff(v * 0.70710678118654752f));
                if (Cf) Cf[off] = v;
                if (Cb) Cb[off] = f2bf(v);
            }
        }
    }
}

// ---------------------------------------------------------------------------
// Weight transpose+cast: W fp32 [K][N] -> Wt bf16 [N][K]
// ---------------------------------------------------------------------------
__global__ __launch_bounds__(256) void wtrans_kernel(
    const float* __restrict__ W, unsigned short* __restrict__ Wt, int K, int N)
{
    __shared__ float t[32][33];
    const int n0 = blockIdx.x * 32, k0 = blockIdx.y * 32;
    const int c = threadIdx.x & 31, r8 = threadIdx.x >> 5;
    #pragma unroll
    for (int i = 0; i < 4; i++) {
        const int r = r8 + i * 8;
        t[r][c] = W[(size_t)(k0 + r) * N + n0 + c];
    }
    __syncthreads();
    #pragma unroll
    for (int i = 0; i < 4; i++) {
        const int r = r8 + i * 8;
        Wt[(size_t)(n0 + r) * K + k0 + c] = f2bf(t[c][r]);
    }
}

// v bf16 [B*1024][1024] -> Vt bf16 [B*1024(d-major)][1024(m)]
__global__ __launch_bounds__(256) void vtrans_kernel(
    const unsigned short* __restrict__ v, unsigned short* __restrict__ Vt)
{
    __shared__ unsigned short t[32][33];
    const int b = blockIdx.z, m0 = blockIdx.x * 32, d0 = blockIdx.y * 32;
    const int c = threadIdx.x & 31, r8 = threadIdx.x >> 5;
    #pragma unroll
    for (int i = 0; i < 4; i++) {
        const int r = r8 + i * 8;
        t[r][c] = v[(size_t)(b * 1024 + m0 + r) * 1024 + d0 + c];
    }
    __syncthreads();
    #pragma unroll
    for (int i = 0; i < 4; i++) {
        const int r = r8 + i * 8;
        Vt[(size_t)(b * 1024 + d0 + r) * 1024 + m0 + c] = t[c][r];
    }
}

// fp32 -> bf16 elementwise (count = grid*256*4)
__global__ __launch_bounds__(256) void castbf_kernel(
    const float* __restrict__ x, unsigned short* __restrict__ y)
{
    const size_t i = ((size_t)blockIdx.x * 256 + threadIdx.x) * 4;
    float4 v = *(const float4*)(x + i);
    ushort4 o;
    o.x = f2bf(v.x); o.y = f2bf(v.y); o.z = f2bf(v.z); o.w = f2bf(v.w);
    *(ushort4*)(y + i) = o;
}

// ---------------------------------------------------------------------------
// LayerNorm over 1024 cols; optional residuals; fp32 and/or bf16 outputs.
// ---------------------------------------------------------------------------
DEV void ln_finish(float4 xv, const float* __restrict__ g,
                   const float* __restrict__ bb, float* __restrict__ outf,
                   unsigned short* __restrict__ outb, size_t base)
{
    float s  = xv.x + xv.y + xv.z + xv.w;
    float s2 = xv.x * xv.x + xv.y * xv.y + xv.z * xv.z + xv.w * xv.w;
    #pragma unroll
    for (int off = 32; off; off >>= 1) {
        s += __shfl_xor(s, off);
        s2 += __shfl_xor(s2, off);
    }
    __shared__ float sa[4], sb[4];
    if ((threadIdx.x & 63) == 0) {
        sa[threadIdx.x >> 6] = s; sb[threadIdx.x >> 6] = s2;
    }
    __syncthreads();
    s  = sa[0] + sa[1] + sa[2] + sa[3];
    s2 = sb[0] + sb[1] + sb[2] + sb[3];
    const float mu  = s * (1.f / 1024.f);
    const float var = fmaxf(s2 * (1.f / 1024.f) - mu * mu, 0.f);
    const float inv = rsqrtf(var + 1e-12f);
    const int tid = threadIdx.x;
    float4 gv = ((const float4*)g)[tid];
    float4 bv = ((const float4*)bb)[tid];
    float4 o;
    o.x = (xv.x - mu) * inv * gv.x + bv.x;
    o.y = (xv.y - mu) * inv * gv.y + bv.y;
    o.z = (xv.z - mu) * inv * gv.z + bv.z;
    o.w = (xv.w - mu) * inv * gv.w + bv.w;
    if (outf) ((float4*)(outf + base))[tid] = o;
    if (outb) {
        ushort4 ob;
        ob.x = f2bf(o.x); ob.y = f2bf(o.y); ob.z = f2bf(o.z); ob.w = f2bf(o.w);
        ((ushort4*)(outb + base))[tid] = ob;
    }
}

__global__ __launch_bounds__(256) void ln_kernel(
    const float* __restrict__ x, const float* __restrict__ r1,
    const float* __restrict__ r2, const float* __restrict__ g,
    const float* __restrict__ bb, float* __restrict__ outf,
    unsigned short* __restrict__ outb)
{
    const size_t base = (size_t)blockIdx.x * 1024;
    const int tid = threadIdx.x;
    float4 xv = ((const float4*)(x + base))[tid];
    if (r1) {
        float4 a = ((const float4*)(r1 + base))[tid];
        xv.x += a.x; xv.y += a.y; xv.z += a.z; xv.w += a.w;
    }
    if (r2) {
        float4 a = ((const float4*)(r2 + base))[tid];
        xv.x += a.x; xv.y += a.y; xv.z += a.z; xv.w += a.w;
    }
    ln_finish(xv, g, bb, outf, outb, base);
}

__global__ __launch_bounds__(256) void gate_ln_kernel(
    const float* __restrict__ gpre, const float* __restrict__ co,
    const float* __restrict__ gn, const float* __restrict__ g,
    const float* __restrict__ bb, float* __restrict__ outf,
    unsigned short* __restrict__ outb)
{
    const size_t base = (size_t)blockIdx.x * 1024;
    const int tid = threadIdx.x;
    float4 gp = ((const float4*)(gpre + base))[tid];
    float4 cv = ((const float4*)(co + base))[tid];
    float4 gv = ((const float4*)(gn + base))[tid];
    float4 xv; float s;
    s = 1.f / (1.f + __expf(-gp.x)); xv.x = s * cv.x + (1.f - s) * gv.x;
    s = 1.f / (1.f + __expf(-gp.y)); xv.y = s * cv.y + (1.f - s) * gv.y;
    s = 1.f / (1.f + __expf(-gp.z)); xv.z = s * cv.z + (1.f - s) * gv.z;
    s = 1.f / (1.f + __expf(-gp.w)); xv.w = s * cv.w + (1.f - s) * gv.w;
    ln_finish(xv, g, bb, outf, outb, base);
}

// ---------------------------------------------------------------------------
// MFMA flash attention + inline focal loss. Block = (n-tile of 64, head, b).
// 4 waves; wave w owns Q rows [w*16, w*16+16). Online softmax; P via LDS
// round-trip (C-layout -> A-layout); V pre-transposed (Vt[b, d, m]).
// ---------------------------------------------------------------------------
__global__ __launch_bounds__(256) void attn_mfma_kernel(
    const unsigned short* __restrict__ qh,  // [B*N,768] bf16
    const unsigned short* __restrict__ kh,  // [B*N,768]
    const unsigned short* __restrict__ q1,  // [B*N,256]
    const unsigned short* __restrict__ k1,  // [B*N,256]
    const unsigned short* __restrict__ Vt,  // [B*1024(d)][1024(m)] bf16
    const float* __restrict__ am,           // [B*N]
    const float* __restrict__ smask,        // [B,3,N,N]
    unsigned short* __restrict__ ctx,       // [B*N,1024] bf16
    float* __restrict__ nump, float* __restrict__ denp)
{
    const int nb = blockIdx.x;              // n0 = nb*64
    const int h  = blockIdx.y;              // 0 = pos head, 1..3 = struct
    const int b  = blockIdx.z;
    const int tid = threadIdx.x;
    const int w = tid >> 6, lane = tid & 63;
    const int l15 = lane & 15, quad = lane >> 4;
    const int n0 = nb * 64;

    __shared__ unsigned short Qs[64 * 264];     // pitch 264 (pad 8)
    __shared__ unsigned short Ks[32 * 264];
    __shared__ unsigned short Vs[256 * 40];     // [d][m] pitch 40
    __shared__ unsigned short Ps[4][16 * 40];   // per-wave P tile

    const unsigned short* qsrc; const unsigned short* ksrc; int kpitch, koff;
    if (h == 0) { qsrc = q1; ksrc = k1; kpitch = 256; koff = 0; }
    else        { qsrc = qh; ksrc = kh; kpitch = 768; koff = (h - 1) * 256; }

    // stage Q (64 x 256 bf16)
    for (int c = tid; c < 2048; c += 256) {
        const int row = c >> 5, kc = (c & 31) * 8;
        *(uint4*)(Qs + row * 264 + kc) =
            *(const uint4*)(qsrc + (size_t)(b * 1024 + n0 + row) * kpitch + koff + kc);
    }
    __syncthreads();
    short8 Qf[8];
    #pragma unroll
    for (int kk = 0; kk < 8; kk++)
        Qf[kk] = *(const short8*)(Qs + (w * 16 + l15) * 264 + kk * 32 + quad * 8);

    float4v O[16];
    #pragma unroll
    for (int i = 0; i < 16; i++) O[i] = (float4v){0.f, 0.f, 0.f, 0.f};
    float mrun[4] = {-1e30f, -1e30f, -1e30f, -1e30f};
    float lrun[4] = {0.f, 0.f, 0.f, 0.f};
    float flsum = 0.f, dencnt = 0.f;
    const int nrow_base = n0 + w * 16 + quad * 4;  // + r = this lane's rows
    float amn[4];
    #pragma unroll
    for (int r = 0; r < 4; r++) amn[r] = am[b * 1024 + nrow_base + r];
    const float* smbase = (h > 0)
        ? smask + ((size_t)b * 3 + (h - 1)) * 1024 * 1024 : nullptr;

    for (int m0 = 0; m0 < 1024; m0 += 32) {
        __syncthreads();
        for (int c = tid; c < 1024; c += 256) {      // K tile 32x256
            const int row = c >> 5, kc = (c & 31) * 8;
            *(uint4*)(Ks + row * 264 + kc) =
                *(const uint4*)(ksrc + (size_t)(b * 1024 + m0 + row) * kpitch + koff + kc);
        }
        for (int c = tid; c < 1024; c += 256) {      // V tile 256(d) x 32(m)
            const int d = c >> 2, mc = (c & 3) * 8;
            *(uint4*)(Vs + d * 40 + mc) =
                *(const uint4*)(Vt + (size_t)(b * 1024 + h * 256 + d) * 1024 + m0 + mc);
        }
        __syncthreads();

        // S = Q K^T (16 x 32 per wave)
        float4v S[2];
        #pragma unroll
        for (int st = 0; st < 2; st++) {
            float4v a = (float4v){0.f, 0.f, 0.f, 0.f};
            #pragma unroll
            for (int kk = 0; kk < 8; kk++) {
                short8 Kf = *(const short8*)(Ks + (st * 16 + l15) * 264 + kk * 32 + quad * 8);
                a = __builtin_amdgcn_mfma_f32_16x16x32_bf16(Qf[kk], Kf, a, 0, 0, 0);
            }
            S[st] = a;
        }

        // masks, focal loss, scaled scores
        float sc[2][4];
        #pragma unroll
        for (int st = 0; st < 2; st++) {
            const int mcol = m0 + st * 16 + l15;
            const float amm = am[b * 1024 + mcol];
            const float am0 = (1.f - amm) * (-10000.f);
            #pragma unroll
            for (int r = 0; r < 4; r++) {
                const float sraw = S[st][r];
                if (h > 0) {
                    const int nrow = nrow_base + r;
                    const float t  = smbase[(size_t)nrow * 1024 + mcol];
                    const float s3 = sraw + am0;
                    const float idxw =
                        ((amn[r] * amm * ((mcol == nrow) ? 0.f : 1.f)) > 0.5f) ? 1.f : 0.f;
                    const float p   = 1.f / (1.f + __expf(-s3));
                    const float spp = softplus_f(-s3);
                    const float spn = softplus_f(s3);
                    flsum += (0.25f * t * (1.f - p) * (1.f - p) * spp
                            + 0.75f * (1.f - t) * p * p * spn) * idxw;
                    dencnt += idxw;
                    sc[st][r] = sraw * 0.0625f + (1.f - t) * (-10000.f);
                } else {
                    sc[st][r] = sraw * 0.0625f + am0;
                }
            }
        }

        // online softmax update (per row, reduce across the 16 col-lanes)
        float e[2][4], alpha[4];
        #pragma unroll
        for (int r = 0; r < 4; r++) {
            float tm = fmaxf(sc[0][r], sc[1][r]);
            #pragma unroll
            for (int off = 8; off; off >>= 1) tm = fmaxf(tm, __shfl_xor(tm, off));
            const float mnew = fmaxf(mrun[r], tm);
            alpha[r] = __expf(mrun[r] - mnew);
            mrun[r] = mnew;
            e[0][r] = __expf(sc[0][r] - mnew);
            e[1][r] = __expf(sc[1][r] - mnew);
            float es = e[0][r] + e[1][r];
            #pragma unroll
            for (int off = 8; off; off >>= 1) es += __shfl_xor(es, off);
            lrun[r] = lrun[r] * alpha[r] + es;
        }
        #pragma unroll
        for (int dt = 0; dt < 16; dt++)
            #pragma unroll
            for (int r = 0; r < 4; r++) O[dt][r] *= alpha[r];

        // P: C-layout -> LDS -> A-layout
        #pragma unroll
        for (int st = 0; st < 2; st++)
            #pragma unroll
            for (int r = 0; r < 4; r++)
                Ps[w][(quad * 4 + r) * 40 + st * 16 + l15] = f2bf(e[st][r]);
        __syncthreads();
        const short8 Pf = *(const short8*)(&Ps[w][l15 * 40 + quad * 8]);
        #pragma unroll
        for (int dt = 0; dt < 16; dt++) {
            short8 Vf = *(const short8*)(Vs + (dt * 16 + l15) * 40 + quad * 8);
            O[dt] = __builtin_amdgcn_mfma_f32_16x16x32_bf16(Pf, Vf, O[dt], 0, 0, 0);
        }
    }

    float rinv[4];
    #pragma unroll
    for (int r = 0; r < 4; r++) rinv[r] = 1.f / lrun[r];
    #pragma unroll
    for (int dt = 0; dt < 16; dt++)
        #pragma unroll
        for (int r = 0; r < 4; r++)
            ctx[(size_t)(b * 1024 + nrow_base + r) * 1024 + h * 256 + dt * 16 + l15]
                = f2bf(O[dt][r] * rinv[r]);

    if (h > 0) {
        const float fb = block_reduce(flsum, 0);
        if (tid == 0) nump[(b * 3 + (h - 1)) * 16 + nb] = fb;
        if (h == 1) {
            const float db = block_reduce(dencnt, 0);
            if (tid == 0) denp[b * 16 + nb] = db;
        }
    }
}

// ---------------------------------------------------------------------------
// Cross attention (fp32, unchanged structure; stores bf16 for cWo GEMM)
// ---------------------------------------------------------------------------
__global__ __launch_bounds__(256) void attn_cross_kernel(
    const float* __restrict__ cq,   // [B*N, 256] (4 x 64)
    const float* __restrict__ ck,   // [B*M, 256]
    const float* __restrict__ cv,   // [B*M, 1024] (4 x 256)
    const float* __restrict__ csm,  // [B,1,N,M]
    unsigned short* __restrict__ cctx)  // [B*N, 1024] bf16
{
    const int n = blockIdx.x, h = blockIdx.y, b = blockIdx.z;
    const int tid = threadIdx.x;
    __shared__ __align__(16) float sq[64];
    __shared__ float sp[512];
    const int bn = b * 1024 + n;

    if (tid < 64) sq[tid] = cq[(size_t)bn * 256 + h * 64 + tid];
    __syncthreads();

    float sc[2], lmax = -3.4e38f;
    #pragma unroll
    for (int i = 0; i < 2; i++) {
        const int m = i * 256 + tid;
        const float4* kr4 = (const float4*)(ck + ((size_t)(b * 512 + m)) * 256 + h * 64);
        const float4* sq4 = (const float4*)sq;
        float acc = 0.f;
        #pragma unroll
        for (int d4 = 0; d4 < 16; d4++) {
            float4 kv = kr4[d4], qv = sq4[d4];
            acc += kv.x * qv.x + kv.y * qv.y + kv.z * qv.z + kv.w * qv.w;
        }
        const float msk = csm[((size_t)b * 1024 + n) * 512 + m];
        sc[i] = acc * 0.125f + (1.f - msk) * (-10000.f);
        lmax = fmaxf(lmax, sc[i]);
    }
    const float bmax = block_reduce(lmax, 1);
    float esum = 0.f;
    #pragma unroll
    for (int i = 0; i < 2; i++) {
        const float e = __expf(sc[i] - bmax);
        sp[i * 256 + tid] = e;
        esum += e;
    }
    const float bsum = block_reduce(esum, 0);
    const float inv = 1.f / bsum;
    __syncthreads();

    float acc = 0.f;
    const float* vb = cv + (size_t)b * 512 * 1024 + h * 256 + tid;
    #pragma unroll 8
    for (int m = 0; m < 512; m++) acc += sp[m] * vb[(size_t)m * 1024];
    cctx[(size_t)bn * 1024 + h * 256 + tid] = f2bf(acc * inv);
}

// loss = sum(nump[384]) / (3 * sum(denp[128])), deterministic
__global__ __launch_bounds__(256) void loss_reduce_kernel(
    const float* __restrict__ nump, const float* __restrict__ denp,
    float* __restrict__ out)
{
    __shared__ double sn[256], sd[256];
    const int tid = threadIdx.x;
    double ns = 0.0, ds = 0.0;
    for (int i = tid; i < 384; i += 256) ns += (double)nump[i];
    for (int i = tid; i < 128; i += 256) ds += (double)denp[i];
    sn[tid] = ns; sd[tid] = ds;
    __syncthreads();
    for (int off = 128; off; off >>= 1) {
        if (tid < off) { sn[tid] += sn[tid + off]; sd[tid] += sd[tid + off]; }
        __syncthreads();
    }
    if (tid == 0) out[0] = (float)(sn[0] / (3.0 * sd[0]));
}

// ---------------------------------------------------------------------------
extern "C" void kernel_launch(void* const* d_in, const int* in_sizes, int n_in,
                              void* d_out, int out_size, void* d_ws, size_t ws_size,
                              hipStream_t stream)
{
    (void)in_sizes; (void)n_in; (void)out_size; (void)ws_size;
    const float* hs   = (const float*)d_in[0];
    const float* am   = (const float*)d_in[1];
    const float* smask= (const float*)d_in[2];
    const float* sent = (const float*)d_in[3];
    const float* ent  = (const float*)d_in[4];
    const float* csm  = (const float*)d_in[5];
    const float* enc  = (const float*)d_in[6];
    const float* Wq  = (const float*)d_in[8];  const float* bq  = (const float*)d_in[9];
    const float* Wk  = (const float*)d_in[10]; const float* bk  = (const float*)d_in[11];
    const float* Wv  = (const float*)d_in[12]; const float* bv  = (const float*)d_in[13];
    const float* Wq1 = (const float*)d_in[14]; const float* bq1 = (const float*)d_in[15];
    const float* Wk1 = (const float*)d_in[16]; const float* bk1 = (const float*)d_in[17];
    const float* ln_g= (const float*)d_in[18]; const float* ln_b= (const float*)d_in[19];
    const float* gW  = (const float*)d_in[20]; const float* gb  = (const float*)d_in[21];
    const float* gng = (const float*)d_in[22]; const float* gnb = (const float*)d_in[23];
    const float* cWq = (const float*)d_in[24]; const float* cbq = (const float*)d_in[25];
    const float* cWk = (const float*)d_in[26]; const float* cbk = (const float*)d_in[27];
    const float* cWv = (const float*)d_in[28]; const float* cbv = (const float*)d_in[29];
    const float* cWo = (const float*)d_in[30]; const float* cbo = (const float*)d_in[31];
    const float* cWg = (const float*)d_in[32]; const float* cbg = (const float*)d_in[33];
    const float* clg = (const float*)d_in[34]; const float* clb = (const float*)d_in[35];
    const float* oW1 = (const float*)d_in[36]; const float* ob1 = (const float*)d_in[37];
    const float* l1g = (const float*)d_in[38]; const float* l1b = (const float*)d_in[39];
    const float* oW2 = (const float*)d_in[40]; const float* ob2 = (const float*)d_in[41];
    const float* oW3 = (const float*)d_in[42]; const float* ob3 = (const float*)d_in[43];
    const float* l3g = (const float*)d_in[44]; const float* l3b = (const float*)d_in[45];
    float* out = (float*)d_out;

    typedef unsigned short ush;
    char* wsb = (char*)d_ws;
    // ---- weight-transpose arena (bf16), 14,155,776 elements ----
    ush* WT   = (ush*)wsb;
    ush* wqT  = WT;             ush* wkT  = WT + 786432;   ush* wvT  = WT + 1572864;
    ush* wq1T = WT + 2621440;   ush* wk1T = WT + 2883584;  ush* gWT_ = WT + 3145728;
    ush* cWqT = WT + 4194304;   ush* cWkT = WT + 4456448;  ush* cWvT = WT + 4718592;
    ush* cWoT = WT + 5767168;   ush* cWgT = WT + 6815744;  ush* oW1T = WT + 8912896;
    ush* oW2T = WT + 9961472;   ush* oW3T = WT + 12058624;
    // ---- activation slabs (byte offsets; lifetimes reused) ----
    ush*  hs_bf   = (ush*)(wsb + 28311552);
    ush*  enc_bf  = (ush*)(wsb + 45088768);
    ush*  q_bf    = (ush*)(wsb + 53477376);
    ush*  k_bf    = (ush*)(wsb + 66060288);
    ush*  v_bf    = (ush*)(wsb + 78643200);
    ush*  Vt      = (ush*)(wsb + 95420416);
    ush*  h1_bf   = (ush*)(wsb + 112197632);
    ush*  q1_bf   = (ush*)(wsb + 128974848);
    ush*  k1_bf   = (ush*)(wsb + 133169152);
    ush*  ctx_bf  = (ush*)(wsb + 137363456);
    float* nump   = (float*)(wsb + 154140672);
    float* denp   = (float*)(wsb + 154142208);
    float* gnn_f  = (float*)(wsb + 154144768);
    float* gnnout_f = (float*)(wsb + 187699200);
    ush*  gnnout_b  = (ush*)(wsb + 221253632);
    // reuse (strictly ordered lifetimes):
    float* cq_f     = (float*)(wsb + 53477376);   // over q_bf
    float* ck_f     = (float*)(wsb + 66060288);   // over k_bf
    float* cv_f     = (float*)(wsb + 78643200);   // over v_bf
    ush*  cctx_b    = (ush*)(wsb + 95420416);     // over Vt
    float* cctxo_f  = (float*)(wsb + 154144768);  // over gnn_f
    ush*  cctxo_b   = (ush*)(wsb + 28311552);     // over hs_bf
    float* gatepre_f= (float*)(wsb + 112197632);  // over h1/q1/k1/ctx
    ush*  crossout_b= (ush*)(wsb + 221253632);    // over gnnout_b
    float* t_f      = (float*)(wsb + 154144768);  // over cctxo_f
    float* h_f      = (float*)(wsb + 187699200);  // over gnnout_f
    ush*  h_b       = (ush*)(wsb + 28311552);     // over cctxo_b
    ush*  h2g_b     = (ush*)(wsb + 45088768);     // over enc/q/k region
    float* h3_f     = (float*)(wsb + 154144768);  // over t_f

    dim3 blk(256);
    // ---- phase 0: casts + weight transposes ----
    castbf_kernel<<<8192, blk, 0, stream>>>(hs, hs_bf);
    castbf_kernel<<<4096, blk, 0, stream>>>(enc, enc_bf);
    wtrans_kernel<<<dim3(768/32, 1024/32), blk, 0, stream>>>(Wq, wqT, 1024, 768);
    wtrans_kernel<<<dim3(768/32, 1024/32), blk, 0, stream>>>(Wk, wkT, 1024, 768);
    wtrans_kernel<<<dim3(32, 32), blk, 0, stream>>>(Wv, wvT, 1024, 1024);
    wtrans_kernel<<<dim3(8, 32), blk, 0, stream>>>(Wq1, wq1T, 1024, 256);
    wtrans_kernel<<<dim3(8, 32), blk, 0, stream>>>(Wk1, wk1T, 1024, 256);
    wtrans_kernel<<<dim3(32, 32), blk, 0, stream>>>(gW, gWT_, 1024, 1024);
    wtrans_kernel<<<dim3(8, 32), blk, 0, stream>>>(cWq, cWqT, 1024, 256);
    wtrans_kernel<<<dim3(8, 32), blk, 0, stream>>>(cWk, cWkT, 1024, 256);
    wtrans_kernel<<<dim3(32, 32), blk, 0, stream>>>(cWv, cWvT, 1024, 1024);
    wtrans_kernel<<<dim3(32, 32), blk, 0, stream>>>(cWo, cWoT, 1024, 1024);
    wtrans_kernel<<<dim3(32, 64), blk, 0, stream>>>(cWg, cWgT, 2048, 1024);
    wtrans_kernel<<<dim3(32, 32), blk, 0, stream>>>(oW1, oW1T, 1024, 1024);
    wtrans_kernel<<<dim3(64, 32), blk, 0, stream>>>(oW2, oW2T, 1024, 2048);
    wtrans_kernel<<<dim3(32, 64), blk, 0, stream>>>(oW3, oW3T, 2048, 1024);
    // ---- phase 1: projections ----
    gemm_bf16_kernel<true,false,false><<<dim3(6, 64), blk, 0, stream>>>(
        hs_bf, 1024, wqT, 1024, bq, nullptr, q_bf, 768, 1024);
    gemm_bf16_kernel<true,false,false><<<dim3(6, 64), blk, 0, stream>>>(
        hs_bf, 1024, wkT, 1024, bk, nullptr, k_bf, 768, 1024);
    gemm_bf16_kernel<true,false,false><<<dim3(8, 64), blk, 0, stream>>>(
        hs_bf, 1024, wvT, 1024, bv, nullptr, v_bf, 1024, 1024);
    ln_kernel<<<8192, blk, 0, stream>>>(hs, sent, ent, ln_g, ln_b, nullptr, h1_bf);
    gemm_bf16_kernel<true,false,false><<<dim3(2, 64), blk, 0, stream>>>(
        h1_bf, 1024, wq1T, 1024, bq1, nullptr, q1_bf, 256, 1024);
    gemm_bf16_kernel<true,false,false><<<dim3(2, 64), blk, 0, stream>>>(
        h1_bf, 1024, wk1T, 1024, bk1, nullptr, k1_bf, 256, 1024);
    vtrans_kernel<<<dim3(32, 32, 8), blk, 0, stream>>>(v_bf, Vt);
    // ---- phase 2: attention + loss ----
    attn_mfma_kernel<<<dim3(16, 4, 8), blk, 0, stream>>>(
        q_bf, k_bf, q1_bf, k1_bf, Vt, am, smask, ctx_bf, nump, denp);
    loss_reduce_kernel<<<1, blk, 0, stream>>>(nump, denp, out + 8388608);
    // ---- phase 3: gnn ----
    gemm_bf16_kernel<true,false,false><<<dim3(8, 64), blk, 0, stream>>>(
        ctx_bf, 1024, gWT_, 1024, gb, gnn_f, nullptr, 1024, 1024);
    ln_kernel<<<8192, blk, 0, stream>>>(gnn_f, nullptr, nullptr, gng, gnb,
                                        gnnout_f, gnnout_b);
    // ---- phase 4: cross attention + gate ----
    gemm_bf16_kernel<true,false,false><<<dim3(2, 64), blk, 0, stream>>>(
        gnnout_b, 1024, cWqT, 1024, cbq, cq_f, nullptr, 256, 1024);
    gemm_bf16_kernel<true,false,false><<<dim3(2, 32), blk, 0, stream>>>(
        enc_bf, 1024, cWkT, 1024, cbk, ck_f, nullptr, 256, 1024);
    gemm_bf16_kernel<true,false,false><<<dim3(8, 32), blk, 0, stream>>>(
        enc_bf, 1024, cWvT, 1024, cbv, cv_f, nullptr, 1024, 1024);
    attn_cross_kernel<<<dim3(1024, 4, 8), blk, 0, stream>>>(
        cq_f, ck_f, cv_f, csm, cctx_b);
    gemm_bf16_kernel<true,false,false><<<dim3(8, 64), blk, 0, stream>>>(
        cctx_b, 1024, cWoT, 1024, cbo, cctxo_f, cctxo_b, 1024, 1024);
    gemm_bf16_kernel<true,false,false><<<dim3(8, 64), blk, 0, stream>>>(
        gnnout_b, 1024, cWgT, 2048, cbg, gatepre_f, nullptr, 1024, 1024);
    gemm_bf16_kernel<false,true,false><<<dim3(8, 64), blk, 0, stream>>>(
        cctxo_b, 1024, cWgT + 1024, 2048, nullptr, gatepre_f, nullptr, 1024, 1024);
    gate_ln_kernel<<<8192, blk, 0, stream>>>(gatepre_f, cctxo_f, gnnout_f,
                                             clg, clb, nullptr, crossout_b);
    // ---- phase 5: output block ----
    gemm_bf16_kernel<true,false,false><<<dim3(8, 64), blk, 0, stream>>>(
        crossout_b, 1024, oW1T, 1024, ob1, t_f, nullptr, 1024, 1024);
    ln_kernel<<<8192, blk, 0, stream>>>(t_f, hs, nullptr, l1g, l1b, h_f, h_b);
    gemm_bf16_kernel<true,false,true><<<dim3(16, 64), blk, 0, stream>>>(
        h_b, 1024, oW2T, 1024, ob2, nullptr, h2g_b, 2048, 1024);
    gemm_bf16_kernel<true,false,false><<<dim3(8, 64), blk, 0, stream>>>(
        h2g_b, 2048, oW3T, 2048, ob3, h3_f, nullptr, 1024, 2048);
    ln_kernel<<<8192, blk, 0, stream>>>(h3_f, h_f, nullptr, l3g, l3b, out, nullptr);
}

// Round 3
// 1388.634 us; speedup vs baseline: 6.9393x; 1.8287x over previous
//
#include <hip/hip_runtime.h>
#include <math.h>

#define DEV __device__ __forceinline__

typedef short short8 __attribute__((ext_vector_type(8)));
typedef float float4v __attribute__((ext_vector_type(4)));

// round-to-nearest-even fp32 -> bf16 (values here are finite; no NaN path)
DEV unsigned short f2bf(float f) {
    union { float f; unsigned u; } v; v.f = f;
    unsigned r = v.u + 0x7FFFu + ((v.u >> 16) & 1u);
    return (unsigned short)(r >> 16);
}

DEV float softplus_f(float x) {            // log(1 + e^x), stable
    return fmaxf(x, 0.f) + log1pf(__expf(-fabsf(x)));
}

// block-wide reduction (256 threads). mode 0 = sum, 1 = max.
DEV float block_reduce(float v, int mode) {
    #pragma unroll
    for (int off = 32; off; off >>= 1) {
        float o = __shfl_xor(v, off);
        v = mode ? fmaxf(v, o) : (v + o);
    }
    __shared__ float sbuf[4];
    __syncthreads();
    if ((threadIdx.x & 63) == 0) sbuf[threadIdx.x >> 6] = v;
    __syncthreads();
    float r = sbuf[0];
    #pragma unroll
    for (int w = 1; w < 4; w++) r = mode ? fmaxf(r, sbuf[w]) : (r + sbuf[w]);
    return r;
}

// ---------------------------------------------------------------------------
// bf16 MFMA GEMM: C[M,N] = A[M,K] @ Wt[N,K]^T (+bias)(+=Cf)(GELU)
// 128x128 tile, BK=32, 256 thr = 4 waves (2x2 of 64x64), 4x4 MFMA tiles/wave.
// Writes fp32 (Cf) and/or bf16 (Cb) when non-null.
// ---------------------------------------------------------------------------
template <bool BIAS, bool ACCUM, bool GELU>
__global__ __launch_bounds__(256) void gemm_bf16_kernel(
    const unsigned short* __restrict__ A, int lda,
    const unsigned short* __restrict__ Bt, int ldb,
    const float* __restrict__ bias,
    float* __restrict__ Cf, unsigned short* __restrict__ Cb,
    int N, int K)
{
    __shared__ unsigned short As[128 * 40];   // [row][k] pitch 40 (pad 8)
    __shared__ unsigned short Bs[128 * 40];   // [n-row][k]
    const int tid = threadIdx.x;
    const int w = tid >> 6, lane = tid & 63;
    const int l15 = lane & 15, quad = lane >> 4;
    const int m0 = blockIdx.y * 128, n0 = blockIdx.x * 128;
    const int wm = (w >> 1) * 64, wn = (w & 1) * 64;

    float4v acc[4][4];
    #pragma unroll
    for (int i = 0; i < 4; i++)
        #pragma unroll
        for (int j = 0; j < 4; j++) acc[i][j] = (float4v){0.f, 0.f, 0.f, 0.f};

    for (int k0 = 0; k0 < K; k0 += 32) {
        __syncthreads();
        #pragma unroll
        for (int i = 0; i < 2; i++) {
            const int c = tid + i * 256;          // 512 chunks of 16B
            const int row = c >> 2, kc = (c & 3) * 8;
            *(uint4*)(As + row * 40 + kc) =
                *(const uint4*)(A + (size_t)(m0 + row) * lda + k0 + kc);
            *(uint4*)(Bs + row * 40 + kc) =
                *(const uint4*)(Bt + (size_t)(n0 + row) * ldb + k0 + kc);
        }
        __syncthreads();
        short8 Af[4], Bf[4];
        #pragma unroll
        for (int mt = 0; mt < 4; mt++)
            Af[mt] = *(const short8*)(As + (wm + mt * 16 + l15) * 40 + quad * 8);
        #pragma unroll
        for (int nt = 0; nt < 4; nt++)
            Bf[nt] = *(const short8*)(Bs + (wn + nt * 16 + l15) * 40 + quad * 8);
        #pragma unroll
        for (int mt = 0; mt < 4; mt++)
            #pragma unroll
            for (int nt = 0; nt < 4; nt++)
                acc[mt][nt] = __builtin_amdgcn_mfma_f32_16x16x32_bf16(
                    Af[mt], Bf[nt], acc[mt][nt], 0, 0, 0);
    }

    #pragma unroll
    for (int nt = 0; nt < 4; nt++) {
        const int n = n0 + wn + nt * 16 + l15;
        const float bv = BIAS ? bias[n] : 0.f;
        #pragma unroll
        for (int mt = 0; mt < 4; mt++) {
            #pragma unroll
            for (int r = 0; r < 4; r++) {
                const int m = m0 + wm + mt * 16 + quad * 4 + r;
                const size_t off = (size_t)m * N + n;
                float v = acc[mt][nt][r] + bv;
                if (ACCUM) v += Cf[off];
                if (GELU) v = 0.5f * v * (1.f + erff(v * 0.70710678118654752f));
                if (Cf) Cf[off] = v;
                if (Cb) Cb[off] = f2bf(v);
            }
        }
    }
}

// ---------------------------------------------------------------------------
// Weight transpose+cast: W fp32 [K][N] -> Wt bf16 [N][K]
// ---------------------------------------------------------------------------
__global__ __launch_bounds__(256) void wtrans_kernel(
    const float* __restrict__ W, unsigned short* __restrict__ Wt, int K, int N)
{
    __shared__ float t[32][33];
    const int n0 = blockIdx.x * 32, k0 = blockIdx.y * 32;
    const int c = threadIdx.x & 31, r8 = threadIdx.x >> 5;
    #pragma unroll
    for (int i = 0; i < 4; i++) {
        const int r = r8 + i * 8;
        t[r][c] = W[(size_t)(k0 + r) * N + n0 + c];
    }
    __syncthreads();
    #pragma unroll
    for (int i = 0; i < 4; i++) {
        const int r = r8 + i * 8;
        Wt[(size_t)(n0 + r) * K + k0 + c] = f2bf(t[c][r]);
    }
}

// bf16 transpose per batch: in [b][R][C] -> out [b][C][R]
__global__ __launch_bounds__(256) void trans_kernel(
    const unsigned short* __restrict__ v, unsigned short* __restrict__ Vt,
    int R, int C)
{
    __shared__ unsigned short t[32][33];
    const int b = blockIdx.z, r0 = blockIdx.x * 32, c0 = blockIdx.y * 32;
    const int c = threadIdx.x & 31, r8 = threadIdx.x >> 5;
    #pragma unroll
    for (int i = 0; i < 4; i++) {
        const int r = r8 + i * 8;
        t[r][c] = v[((size_t)b * R + r0 + r) * C + c0 + c];
    }
    __syncthreads();
    #pragma unroll
    for (int i = 0; i < 4; i++) {
        const int r = r8 + i * 8;
        Vt[((size_t)b * C + c0 + r) * R + r0 + c] = t[c][r];
    }
}

// fp32 -> bf16 elementwise (count = grid*256*4)
__global__ __launch_bounds__(256) void castbf_kernel(
    const float* __restrict__ x, unsigned short* __restrict__ y)
{
    const size_t i = ((size_t)blockIdx.x * 256 + threadIdx.x) * 4;
    float4 v = *(const float4*)(x + i);
    ushort4 o;
    o.x = f2bf(v.x); o.y = f2bf(v.y); o.z = f2bf(v.z); o.w = f2bf(v.w);
    *(ushort4*)(y + i) = o;
}

// ---------------------------------------------------------------------------
// LayerNorm over 1024 cols; optional residuals; fp32 and/or bf16 outputs.
// ---------------------------------------------------------------------------
DEV void ln_finish(float4 xv, const float* __restrict__ g,
                   const float* __restrict__ bb, float* __restrict__ outf,
                   unsigned short* __restrict__ outb, size_t base)
{
    float s  = xv.x + xv.y + xv.z + xv.w;
    float s2 = xv.x * xv.x + xv.y * xv.y + xv.z * xv.z + xv.w * xv.w;
    #pragma unroll
    for (int off = 32; off; off >>= 1) {
        s += __shfl_xor(s, off);
        s2 += __shfl_xor(s2, off);
    }
    __shared__ float sa[4], sb[4];
    if ((threadIdx.x & 63) == 0) {
        sa[threadIdx.x >> 6] = s; sb[threadIdx.x >> 6] = s2;
    }
    __syncthreads();
    s  = sa[0] + sa[1] + sa[2] + sa[3];
    s2 = sb[0] + sb[1] + sb[2] + sb[3];
    const float mu  = s * (1.f / 1024.f);
    const float var = fmaxf(s2 * (1.f / 1024.f) - mu * mu, 0.f);
    const float inv = rsqrtf(var + 1e-12f);
    const int tid = threadIdx.x;
    float4 gv = ((const float4*)g)[tid];
    float4 bv = ((const float4*)bb)[tid];
    float4 o;
    o.x = (xv.x - mu) * inv * gv.x + bv.x;
    o.y = (xv.y - mu) * inv * gv.y + bv.y;
    o.z = (xv.z - mu) * inv * gv.z + bv.z;
    o.w = (xv.w - mu) * inv * gv.w + bv.w;
    if (outf) ((float4*)(outf + base))[tid] = o;
    if (outb) {
        ushort4 ob;
        ob.x = f2bf(o.x); ob.y = f2bf(o.y); ob.z = f2bf(o.z); ob.w = f2bf(o.w);
        ((ushort4*)(outb + base))[tid] = ob;
    }
}

__global__ __launch_bounds__(256) void ln_kernel(
    const float* __restrict__ x, const float* __restrict__ r1,
    const float* __restrict__ r2, const float* __restrict__ g,
    const float* __restrict__ bb, float* __restrict__ outf,
    unsigned short* __restrict__ outb)
{
    const size_t base = (size_t)blockIdx.x * 1024;
    const int tid = threadIdx.x;
    float4 xv = ((const float4*)(x + base))[tid];
    if (r1) {
        float4 a = ((const float4*)(r1 + base))[tid];
        xv.x += a.x; xv.y += a.y; xv.z += a.z; xv.w += a.w;
    }
    if (r2) {
        float4 a = ((const float4*)(r2 + base))[tid];
        xv.x += a.x; xv.y += a.y; xv.z += a.z; xv.w += a.w;
    }
    ln_finish(xv, g, bb, outf, outb, base);
}

__global__ __launch_bounds__(256) void gate_ln_kernel(
    const float* __restrict__ gpre, const float* __restrict__ co,
    const float* __restrict__ gn, const float* __restrict__ g,
    const float* __restrict__ bb, float* __restrict__ outf,
    unsigned short* __restrict__ outb)
{
    const size_t base = (size_t)blockIdx.x * 1024;
    const int tid = threadIdx.x;
    float4 gp = ((const float4*)(gpre + base))[tid];
    float4 cv = ((const float4*)(co + base))[tid];
    float4 gv = ((const float4*)(gn + base))[tid];
    float4 xv; float s;
    s = 1.f / (1.f + __expf(-gp.x)); xv.x = s * cv.x + (1.f - s) * gv.x;
    s = 1.f / (1.f + __expf(-gp.y)); xv.y = s * cv.y + (1.f - s) * gv.y;
    s = 1.f / (1.f + __expf(-gp.z)); xv.z = s * cv.z + (1.f - s) * gv.z;
    s = 1.f / (1.f + __expf(-gp.w)); xv.w = s * cv.w + (1.f - s) * gv.w;
    ln_finish(xv, g, bb, outf, outb, base);
}

// ---------------------------------------------------------------------------
// MFMA flash attention + inline focal loss. Block = (n-tile of 64, head, b).
// 4 waves; wave w owns Q rows [w*16, w*16+16). Online softmax; P via LDS
// round-trip (C-layout -> A-layout); V pre-transposed (Vt[b, d, m]).
// ---------------------------------------------------------------------------
__global__ __launch_bounds__(256) void attn_mfma_kernel(
    const unsigned short* __restrict__ qh,  // [B*N,768] bf16
    const unsigned short* __restrict__ kh,  // [B*N,768]
    const unsigned short* __restrict__ q1,  // [B*N,256]
    const unsigned short* __restrict__ k1,  // [B*N,256]
    const unsigned short* __restrict__ Vt,  // [B*1024(d)][1024(m)] bf16
    const float* __restrict__ am,           // [B*N]
    const float* __restrict__ smask,        // [B,3,N,N]
    unsigned short* __restrict__ ctx,       // [B*N,1024] bf16
    float* __restrict__ nump, float* __restrict__ denp)
{
    const int nb = blockIdx.x;              // n0 = nb*64
    const int h  = blockIdx.y;              // 0 = pos head, 1..3 = struct
    const int b  = blockIdx.z;
    const int tid = threadIdx.x;
    const int w = tid >> 6, lane = tid & 63;
    const int l15 = lane & 15, quad = lane >> 4;
    const int n0 = nb * 64;

    __shared__ unsigned short Qs[64 * 264];     // pitch 264 (pad 8)
    __shared__ unsigned short Ks[32 * 264];
    __shared__ unsigned short Vs[256 * 40];     // [d][m] pitch 40
    __shared__ unsigned short Ps[4][16 * 40];   // per-wave P tile

    const unsigned short* qsrc; const unsigned short* ksrc; int kpitch, koff;
    if (h == 0) { qsrc = q1; ksrc = k1; kpitch = 256; koff = 0; }
    else        { qsrc = qh; ksrc = kh; kpitch = 768; koff = (h - 1) * 256; }

    // stage Q (64 x 256 bf16)
    for (int c = tid; c < 2048; c += 256) {
        const int row = c >> 5, kc = (c & 31) * 8;
        *(uint4*)(Qs + row * 264 + kc) =
            *(const uint4*)(qsrc + (size_t)(b * 1024 + n0 + row) * kpitch + koff + kc);
    }
    __syncthreads();
    short8 Qf[8];
    #pragma unroll
    for (int kk = 0; kk < 8; kk++)
        Qf[kk] = *(const short8*)(Qs + (w * 16 + l15) * 264 + kk * 32 + quad * 8);

    float4v O[16];
    #pragma unroll
    for (int i = 0; i < 16; i++) O[i] = (float4v){0.f, 0.f, 0.f, 0.f};
    float mrun[4] = {-1e30f, -1e30f, -1e30f, -1e30f};
    float lrun[4] = {0.f, 0.f, 0.f, 0.f};
    float flsum = 0.f, dencnt = 0.f;
    const int nrow_base = n0 + w * 16 + quad * 4;  // + r = this lane's rows
    float amn[4];
    #pragma unroll
    for (int r = 0; r < 4; r++) amn[r] = am[b * 1024 + nrow_base + r];
    const float* smbase = (h > 0)
        ? smask + ((size_t)b * 3 + (h - 1)) * 1024 * 1024 : nullptr;

    for (int m0 = 0; m0 < 1024; m0 += 32) {
        __syncthreads();
        for (int c = tid; c < 1024; c += 256) {      // K tile 32x256
            const int row = c >> 5, kc = (c & 31) * 8;
            *(uint4*)(Ks + row * 264 + kc) =
                *(const uint4*)(ksrc + (size_t)(b * 1024 + m0 + row) * kpitch + koff + kc);
        }
        for (int c = tid; c < 1024; c += 256) {      // V tile 256(d) x 32(m)
            const int d = c >> 2, mc = (c & 3) * 8;
            *(uint4*)(Vs + d * 40 + mc) =
                *(const uint4*)(Vt + (size_t)(b * 1024 + h * 256 + d) * 1024 + m0 + mc);
        }
        __syncthreads();

        // S = Q K^T (16 x 32 per wave)
        float4v S[2];
        #pragma unroll
        for (int st = 0; st < 2; st++) {
            float4v a = (float4v){0.f, 0.f, 0.f, 0.f};
            #pragma unroll
            for (int kk = 0; kk < 8; kk++) {
                short8 Kf = *(const short8*)(Ks + (st * 16 + l15) * 264 + kk * 32 + quad * 8);
                a = __builtin_amdgcn_mfma_f32_16x16x32_bf16(Qf[kk], Kf, a, 0, 0, 0);
            }
            S[st] = a;
        }

        // masks, focal loss, scaled scores
        float sc[2][4];
        #pragma unroll
        for (int st = 0; st < 2; st++) {
            const int mcol = m0 + st * 16 + l15;
            const float amm = am[b * 1024 + mcol];
            const float am0 = (1.f - amm) * (-10000.f);
            #pragma unroll
            for (int r = 0; r < 4; r++) {
                const float sraw = S[st][r];
                if (h > 0) {
                    const int nrow = nrow_base + r;
                    const float t  = smbase[(size_t)nrow * 1024 + mcol];
                    const float s3 = sraw + am0;
                    const float idxw =
                        ((amn[r] * amm * ((mcol == nrow) ? 0.f : 1.f)) > 0.5f) ? 1.f : 0.f;
                    const float p   = 1.f / (1.f + __expf(-s3));
                    const float spp = softplus_f(-s3);
                    const float spn = softplus_f(s3);
                    flsum += (0.25f * t * (1.f - p) * (1.f - p) * spp
                            + 0.75f * (1.f - t) * p * p * spn) * idxw;
                    dencnt += idxw;
                    sc[st][r] = sraw * 0.0625f + (1.f - t) * (-10000.f);
                } else {
                    sc[st][r] = sraw * 0.0625f + am0;
                }
            }
        }

        // online softmax update (per row, reduce across the 16 col-lanes)
        float e[2][4], alpha[4];
        #pragma unroll
        for (int r = 0; r < 4; r++) {
            float tm = fmaxf(sc[0][r], sc[1][r]);
            #pragma unroll
            for (int off = 8; off; off >>= 1) tm = fmaxf(tm, __shfl_xor(tm, off));
            const float mnew = fmaxf(mrun[r], tm);
            alpha[r] = __expf(mrun[r] - mnew);
            mrun[r] = mnew;
            e[0][r] = __expf(sc[0][r] - mnew);
            e[1][r] = __expf(sc[1][r] - mnew);
            float es = e[0][r] + e[1][r];
            #pragma unroll
            for (int off = 8; off; off >>= 1) es += __shfl_xor(es, off);
            lrun[r] = lrun[r] * alpha[r] + es;
        }
        #pragma unroll
        for (int dt = 0; dt < 16; dt++)
            #pragma unroll
            for (int r = 0; r < 4; r++) O[dt][r] *= alpha[r];

        // P: C-layout -> LDS -> A-layout
        #pragma unroll
        for (int st = 0; st < 2; st++)
            #pragma unroll
            for (int r = 0; r < 4; r++)
                Ps[w][(quad * 4 + r) * 40 + st * 16 + l15] = f2bf(e[st][r]);
        __syncthreads();
        const short8 Pf = *(const short8*)(&Ps[w][l15 * 40 + quad * 8]);
        #pragma unroll
        for (int dt = 0; dt < 16; dt++) {
            short8 Vf = *(const short8*)(Vs + (dt * 16 + l15) * 40 + quad * 8);
            O[dt] = __builtin_amdgcn_mfma_f32_16x16x32_bf16(Pf, Vf, O[dt], 0, 0, 0);
        }
    }

    float rinv[4];
    #pragma unroll
    for (int r = 0; r < 4; r++) rinv[r] = 1.f / lrun[r];
    #pragma unroll
    for (int dt = 0; dt < 16; dt++)
        #pragma unroll
        for (int r = 0; r < 4; r++)
            ctx[(size_t)(b * 1024 + nrow_base + r) * 1024 + h * 256 + dt * 16 + l15]
                = f2bf(O[dt][r] * rinv[r]);

    if (h > 0) {
        const float fb = block_reduce(flsum, 0);
        if (tid == 0) nump[(b * 3 + (h - 1)) * 16 + nb] = fb;
        if (h == 1) {
            const float db = block_reduce(dencnt, 0);
            if (tid == 0) denp[b * 16 + nb] = db;
        }
    }
}

// ---------------------------------------------------------------------------
// MFMA cross attention. Block = (n-tile of 64, head, b). qk-dim 64, v-dim 256,
// M = 512 keys. Same structure as attn_mfma_kernel, no focal loss.
// ---------------------------------------------------------------------------
__global__ __launch_bounds__(256) void cross_mfma_kernel(
    const unsigned short* __restrict__ cq,   // [B*N, 256] bf16 (4 heads x 64)
    const unsigned short* __restrict__ ck,   // [B*512, 256] bf16
    const unsigned short* __restrict__ cvt,  // [B][1024(d)][512(m)] bf16
    const float* __restrict__ csm,           // [B*1024, 512]
    unsigned short* __restrict__ cctx)       // [B*N, 1024] bf16
{
    const int nb = blockIdx.x;               // 16 tiles of 64 q-rows
    const int h  = blockIdx.y;               // 4 heads
    const int b  = blockIdx.z;
    const int tid = threadIdx.x;
    const int w = tid >> 6, lane = tid & 63;
    const int l15 = lane & 15, quad = lane >> 4;
    const int n0 = nb * 64;

    __shared__ unsigned short Qs[64 * 72];    // 64 x 64, pitch 72
    __shared__ unsigned short Ks[32 * 72];
    __shared__ unsigned short Vs[256 * 40];   // [d][m] pitch 40
    __shared__ unsigned short Ps[4][16 * 40];

    // stage Q (64 rows x 64 k)
    for (int c = tid; c < 512; c += 256) {
        const int row = c >> 3, kc = (c & 7) * 8;
        *(uint4*)(Qs + row * 72 + kc) =
            *(const uint4*)(cq + (size_t)(b * 1024 + n0 + row) * 256 + h * 64 + kc);
    }
    __syncthreads();
    short8 Qf[2];
    #pragma unroll
    for (int kk = 0; kk < 2; kk++)
        Qf[kk] = *(const short8*)(Qs + (w * 16 + l15) * 72 + kk * 32 + quad * 8);

    float4v O[16];
    #pragma unroll
    for (int i = 0; i < 16; i++) O[i] = (float4v){0.f, 0.f, 0.f, 0.f};
    float mrun[4] = {-1e30f, -1e30f, -1e30f, -1e30f};
    float lrun[4] = {0.f, 0.f, 0.f, 0.f};
    const int nrow_base = n0 + w * 16 + quad * 4;

    for (int m0 = 0; m0 < 512; m0 += 32) {
        __syncthreads();
        if (tid < 256) {                         // K tile 32 x 64
            const int row = tid >> 3, kc = (tid & 7) * 8;
            *(uint4*)(Ks + row * 72 + kc) =
                *(const uint4*)(ck + (size_t)(b * 512 + m0 + row) * 256 + h * 64 + kc);
        }
        for (int c = tid; c < 1024; c += 256) {  // V tile 256(d) x 32(m)
            const int d = c >> 2, mc = (c & 3) * 8;
            *(uint4*)(Vs + d * 40 + mc) =
                *(const uint4*)(cvt + (size_t)(b * 1024 + h * 256 + d) * 512 + m0 + mc);
        }
        __syncthreads();

        // S = Q K^T (16 x 32 per wave)
        float sc[2][4];
        #pragma unroll
        for (int st = 0; st < 2; st++) {
            float4v a = (float4v){0.f, 0.f, 0.f, 0.f};
            #pragma unroll
            for (int kk = 0; kk < 2; kk++) {
                short8 Kf = *(const short8*)(Ks + (st * 16 + l15) * 72 + kk * 32 + quad * 8);
                a = __builtin_amdgcn_mfma_f32_16x16x32_bf16(Qf[kk], Kf, a, 0, 0, 0);
            }
            const int mcol = m0 + st * 16 + l15;
            #pragma unroll
            for (int r = 0; r < 4; r++) {
                const float msk = csm[(size_t)(b * 1024 + nrow_base + r) * 512 + mcol];
                sc[st][r] = a[r] * 0.125f + (1.f - msk) * (-10000.f);
            }
        }

        // online softmax update
        float e[2][4], alpha[4];
        #pragma unroll
        for (int r = 0; r < 4; r++) {
            float tm = fmaxf(sc[0][r], sc[1][r]);
            #pragma unroll
            for (int off = 8; off; off >>= 1) tm = fmaxf(tm, __shfl_xor(tm, off));
            const float mnew = fmaxf(mrun[r], tm);
            alpha[r] = __expf(mrun[r] - mnew);
            mrun[r] = mnew;
            e[0][r] = __expf(sc[0][r] - mnew);
            e[1][r] = __expf(sc[1][r] - mnew);
            float es = e[0][r] + e[1][r];
            #pragma unroll
            for (int off = 8; off; off >>= 1) es += __shfl_xor(es, off);
            lrun[r] = lrun[r] * alpha[r] + es;
        }
        #pragma unroll
        for (int dt = 0; dt < 16; dt++)
            #pragma unroll
            for (int r = 0; r < 4; r++) O[dt][r] *= alpha[r];

        // P: C-layout -> LDS -> A-layout
        #pragma unroll
        for (int st = 0; st < 2; st++)
            #pragma unroll
            for (int r = 0; r < 4; r++)
                Ps[w][(quad * 4 + r) * 40 + st * 16 + l15] = f2bf(e[st][r]);
        __syncthreads();
        const short8 Pf = *(const short8*)(&Ps[w][l15 * 40 + quad * 8]);
        #pragma unroll
        for (int dt = 0; dt < 16; dt++) {
            short8 Vf = *(const short8*)(Vs + (dt * 16 + l15) * 40 + quad * 8);
            O[dt] = __builtin_amdgcn_mfma_f32_16x16x32_bf16(Pf, Vf, O[dt], 0, 0, 0);
        }
    }

    float rinv[4];
    #pragma unroll
    for (int r = 0; r < 4; r++) rinv[r] = 1.f / lrun[r];
    #pragma unroll
    for (int dt = 0; dt < 16; dt++)
        #pragma unroll
        for (int r = 0; r < 4; r++)
            cctx[(size_t)(b * 1024 + nrow_base + r) * 1024 + h * 256 + dt * 16 + l15]
                = f2bf(O[dt][r] * rinv[r]);
}

// loss = sum(nump[384]) / (3 * sum(denp[128])), deterministic
__global__ __launch_bounds__(256) void loss_reduce_kernel(
    const float* __restrict__ nump, const float* __restrict__ denp,
    float* __restrict__ out)
{
    __shared__ double sn[256], sd[256];
    const int tid = threadIdx.x;
    double ns = 0.0, ds = 0.0;
    for (int i = tid; i < 384; i += 256) ns += (double)nump[i];
    for (int i = tid; i < 128; i += 256) ds += (double)denp[i];
    sn[tid] = ns; sd[tid] = ds;
    __syncthreads();
    for (int off = 128; off; off >>= 1) {
        if (tid < off) { sn[tid] += sn[tid + off]; sd[tid] += sd[tid + off]; }
        __syncthreads();
    }
    if (tid == 0) out[0] = (float)(sn[0] / (3.0 * sd[0]));
}

// ---------------------------------------------------------------------------
extern "C" void kernel_launch(void* const* d_in, const int* in_sizes, int n_in,
                              void* d_out, int out_size, void* d_ws, size_t ws_size,
                              hipStream_t stream)
{
    (void)in_sizes; (void)n_in; (void)out_size; (void)ws_size;
    const float* hs   = (const float*)d_in[0];
    const float* am   = (const float*)d_in[1];
    const float* smask= (const float*)d_in[2];
    const float* sent = (const float*)d_in[3];
    const float* ent  = (const float*)d_in[4];
    const float* csm  = (const float*)d_in[5];
    const float* enc  = (const float*)d_in[6];
    const float* Wq  = (const float*)d_in[8];  const float* bq  = (const float*)d_in[9];
    const float* Wk  = (const float*)d_in[10]; const float* bk  = (const float*)d_in[11];
    const float* Wv  = (const float*)d_in[12]; const float* bv  = (const float*)d_in[13];
    const float* Wq1 = (const float*)d_in[14]; const float* bq1 = (const float*)d_in[15];
    const float* Wk1 = (const float*)d_in[16]; const float* bk1 = (const float*)d_in[17];
    const float* ln_g= (const float*)d_in[18]; const float* ln_b= (const float*)d_in[19];
    const float* gW  = (const float*)d_in[20]; const float* gb  = (const float*)d_in[21];
    const float* gng = (const float*)d_in[22]; const float* gnb = (const float*)d_in[23];
    const float* cWq = (const float*)d_in[24]; const float* cbq = (const float*)d_in[25];
    const float* cWk = (const float*)d_in[26]; const float* cbk = (const float*)d_in[27];
    const float* cWv = (const float*)d_in[28]; const float* cbv = (const float*)d_in[29];
    const float* cWo = (const float*)d_in[30]; const float* cbo = (const float*)d_in[31];
    const float* cWg = (const float*)d_in[32]; const float* cbg = (const float*)d_in[33];
    const float* clg = (const float*)d_in[34]; const float* clb = (const float*)d_in[35];
    const float* oW1 = (const float*)d_in[36]; const float* ob1 = (const float*)d_in[37];
    const float* l1g = (const float*)d_in[38]; const float* l1b = (const float*)d_in[39];
    const float* oW2 = (const float*)d_in[40]; const float* ob2 = (const float*)d_in[41];
    const float* oW3 = (const float*)d_in[42]; const float* ob3 = (const float*)d_in[43];
    const float* l3g = (const float*)d_in[44]; const float* l3b = (const float*)d_in[45];
    float* out = (float*)d_out;

    typedef unsigned short ush;
    char* wsb = (char*)d_ws;
    // ---- weight-transpose arena (bf16), 14,155,776 elements ----
    ush* WT   = (ush*)wsb;
    ush* wqT  = WT;             ush* wkT  = WT + 786432;   ush* wvT  = WT + 1572864;
    ush* wq1T = WT + 2621440;   ush* wk1T = WT + 2883584;  ush* gWT_ = WT + 3145728;
    ush* cWqT = WT + 4194304;   ush* cWkT = WT + 4456448;  ush* cWvT = WT + 4718592;
    ush* cWoT = WT + 5767168;   ush* cWgT = WT + 6815744;  ush* oW1T = WT + 8912896;
    ush* oW2T = WT + 9961472;   ush* oW3T = WT + 12058624;
    // ---- activation slabs (byte offsets; lifetimes reused) ----
    ush*  hs_bf   = (ush*)(wsb + 28311552);
    ush*  enc_bf  = (ush*)(wsb + 45088768);
    ush*  q_bf    = (ush*)(wsb + 53477376);
    ush*  k_bf    = (ush*)(wsb + 66060288);
    ush*  v_bf    = (ush*)(wsb + 78643200);
    ush*  Vt      = (ush*)(wsb + 95420416);
    ush*  h1_bf   = (ush*)(wsb + 112197632);
    ush*  q1_bf   = (ush*)(wsb + 128974848);
    ush*  k1_bf   = (ush*)(wsb + 133169152);
    ush*  ctx_bf  = (ush*)(wsb + 137363456);
    float* nump   = (float*)(wsb + 154140672);
    float* denp   = (float*)(wsb + 154142208);
    float* gnn_f  = (float*)(wsb + 154144768);
    float* gnnout_f = (float*)(wsb + 187699200);
    ush*  gnnout_b  = (ush*)(wsb + 221253632);
    // reuse (strictly ordered lifetimes):
    ush*  cq_b      = (ush*)(wsb + 53477376);     // over q_bf
    ush*  ck_b      = (ush*)(wsb + 66060288);     // over k_bf
    ush*  cv_b      = (ush*)(wsb + 78643200);     // over v_bf
    ush*  cctx_b    = (ush*)(wsb + 95420416);     // over Vt
    ush*  cvt       = (ush*)(wsb + 238030848);    // after gnnout_b
    float* cctxo_f  = (float*)(wsb + 154144768);  // over gnn_f
    ush*  cctxo_b   = (ush*)(wsb + 28311552);     // over hs_bf
    float* gatepre_f= (float*)(wsb + 112197632);  // over h1/q1/k1/ctx
    ush*  crossout_b= (ush*)(wsb + 221253632);    // over gnnout_b
    float* t_f      = (float*)(wsb + 154144768);  // over cctxo_f
    float* h_f      = (float*)(wsb + 187699200);  // over gnnout_f
    ush*  h_b       = (ush*)(wsb + 28311552);     // over cctxo_b
    ush*  h2g_b     = (ush*)(wsb + 45088768);     // over enc/q/k region
    float* h3_f     = (float*)(wsb + 154144768);  // over t_f

    dim3 blk(256);
    // ---- phase 0: casts + weight transposes ----
    castbf_kernel<<<8192, blk, 0, stream>>>(hs, hs_bf);
    castbf_kernel<<<4096, blk, 0, stream>>>(enc, enc_bf);
    wtrans_kernel<<<dim3(768/32, 1024/32), blk, 0, stream>>>(Wq, wqT, 1024, 768);
    wtrans_kernel<<<dim3(768/32, 1024/32), blk, 0, stream>>>(Wk, wkT, 1024, 768);
    wtrans_kernel<<<dim3(32, 32), blk, 0, stream>>>(Wv, wvT, 1024, 1024);
    wtrans_kernel<<<dim3(8, 32), blk, 0, stream>>>(Wq1, wq1T, 1024, 256);
    wtrans_kernel<<<dim3(8, 32), blk, 0, stream>>>(Wk1, wk1T, 1024, 256);
    wtrans_kernel<<<dim3(32, 32), blk, 0, stream>>>(gW, gWT_, 1024, 1024);
    wtrans_kernel<<<dim3(8, 32), blk, 0, stream>>>(cWq, cWqT, 1024, 256);
    wtrans_kernel<<<dim3(8, 32), blk, 0, stream>>>(cWk, cWkT, 1024, 256);
    wtrans_kernel<<<dim3(32, 32), blk, 0, stream>>>(cWv, cWvT, 1024, 1024);
    wtrans_kernel<<<dim3(32, 32), blk, 0, stream>>>(cWo, cWoT, 1024, 1024);
    wtrans_kernel<<<dim3(32, 64), blk, 0, stream>>>(cWg, cWgT, 2048, 1024);
    wtrans_kernel<<<dim3(32, 32), blk, 0, stream>>>(oW1, oW1T, 1024, 1024);
    wtrans_kernel<<<dim3(64, 32), blk, 0, stream>>>(oW2, oW2T, 1024, 2048);
    wtrans_kernel<<<dim3(32, 64), blk, 0, stream>>>(oW3, oW3T, 2048, 1024);
    // ---- phase 1: projections ----
    gemm_bf16_kernel<true,false,false><<<dim3(6, 64), blk, 0, stream>>>(
        hs_bf, 1024, wqT, 1024, bq, nullptr, q_bf, 768, 1024);
    gemm_bf16_kernel<true,false,false><<<dim3(6, 64), blk, 0, stream>>>(
        hs_bf, 1024, wkT, 1024, bk, nullptr, k_bf, 768, 1024);
    gemm_bf16_kernel<true,false,false><<<dim3(8, 64), blk, 0, stream>>>(
        hs_bf, 1024, wvT, 1024, bv, nullptr, v_bf, 1024, 1024);
    ln_kernel<<<8192, blk, 0, stream>>>(hs, sent, ent, ln_g, ln_b, nullptr, h1_bf);
    gemm_bf16_kernel<true,false,false><<<dim3(2, 64), blk, 0, stream>>>(
        h1_bf, 1024, wq1T, 1024, bq1, nullptr, q1_bf, 256, 1024);
    gemm_bf16_kernel<true,false,false><<<dim3(2, 64), blk, 0, stream>>>(
        h1_bf, 1024, wk1T, 1024, bk1, nullptr, k1_bf, 256, 1024);
    trans_kernel<<<dim3(32, 32, 8), blk, 0, stream>>>(v_bf, Vt, 1024, 1024);
    // ---- phase 2: attention + loss ----
    attn_mfma_kernel<<<dim3(16, 4, 8), blk, 0, stream>>>(
        q_bf, k_bf, q1_bf, k1_bf, Vt, am, smask, ctx_bf, nump, denp);
    loss_reduce_kernel<<<1, blk, 0, stream>>>(nump, denp, out + 8388608);
    // ---- phase 3: gnn ----
    gemm_bf16_kernel<true,false,false><<<dim3(8, 64), blk, 0, stream>>>(
        ctx_bf, 1024, gWT_, 1024, gb, gnn_f, nullptr, 1024, 1024);
    ln_kernel<<<8192, blk, 0, stream>>>(gnn_f, nullptr, nullptr, gng, gnb,
                                        gnnout_f, gnnout_b);
    // ---- phase 4: cross attention + gate ----
    gemm_bf16_kernel<true,false,false><<<dim3(2, 64), blk, 0, stream>>>(
        gnnout_b, 1024, cWqT, 1024, cbq, nullptr, cq_b, 256, 1024);
    gemm_bf16_kernel<true,false,false><<<dim3(2, 32), blk, 0, stream>>>(
        enc_bf, 1024, cWkT, 1024, cbk, nullptr, ck_b, 256, 1024);
    gemm_bf16_kernel<true,false,false><<<dim3(8, 32), blk, 0, stream>>>(
        enc_bf, 1024, cWvT, 1024, cbv, nullptr, cv_b, 1024, 1024);
    trans_kernel<<<dim3(16, 32, 8), blk, 0, stream>>>(cv_b, cvt, 512, 1024);
    cross_mfma_kernel<<<dim3(16, 4, 8), blk, 0, stream>>>(
        cq_b, ck_b, cvt, csm, cctx_b);
    gemm_bf16_kernel<true,false,false><<<dim3(8, 64), blk, 0, stream>>>(
        cctx_b, 1024, cWoT, 1024, cbo, cctxo_f, cctxo_b, 1024, 1024);
    gemm_bf16_kernel<true,false,false><<<dim3(8, 64), blk, 0, stream>>>(
        gnnout_b, 1024, cWgT, 2048, cbg, gatepre_f, nullptr, 1024, 1024);
    gemm_bf16_kernel<false,true,false><<<dim3(8, 64), blk, 0, stream>>>(
        cctxo_b, 1024, cWgT + 1024, 2048, nullptr, gatepre_f, nullptr, 1024, 1024);
    gate_ln_kernel<<<8192, blk, 0, stream>>>(gatepre_f, cctxo_f, gnnout_f,
                                             clg, clb, nullptr, crossout_b);
    // ---- phase 5: output block ----
    gemm_bf16_kernel<true,false,false><<<dim3(8, 64), blk, 0, stream>>>(
        crossout_b, 1024, oW1T, 1024, ob1, t_f, nullptr, 1024, 1024);
    ln_kernel<<<8192, blk, 0, stream>>>(t_f, hs, nullptr, l1g, l1b, h_f, h_b);
    gemm_bf16_kernel<true,false,true><<<dim3(16, 64), blk, 0, stream>>>(
        h_b, 1024, oW2T, 1024, ob2, nullptr, h2g_b, 2048, 1024);
    gemm_bf16_kernel<true,false,false><<<dim3(8, 64), blk, 0, stream>>>(
        h2g_b, 2048, oW3T, 2048, ob3, h3_f, nullptr, 1024, 2048);
    ln_kernel<<<8192, blk, 0, stream>>>(h3_f, h_f, nullptr, l3g, l3b, out, nullptr);
}

// Round 4
// 1313.775 us; speedup vs baseline: 7.3347x; 1.0570x over previous
//
#include <hip/hip_runtime.h>
#include <math.h>

#define DEV __device__ __forceinline__

typedef short short8 __attribute__((ext_vector_type(8)));
typedef float float4v __attribute__((ext_vector_type(4)));

// round-to-nearest-even fp32 -> bf16 (values here are finite; no NaN path)
DEV unsigned short f2bf(float f) {
    union { float f; unsigned u; } v; v.f = f;
    unsigned r = v.u + 0x7FFFu + ((v.u >> 16) & 1u);
    return (unsigned short)(r >> 16);
}

// block-wide reduction (256 threads). mode 0 = sum, 1 = max.
DEV float block_reduce(float v, int mode) {
    #pragma unroll
    for (int off = 32; off; off >>= 1) {
        float o = __shfl_xor(v, off);
        v = mode ? fmaxf(v, o) : (v + o);
    }
    __shared__ float sbuf[4];
    __syncthreads();
    if ((threadIdx.x & 63) == 0) sbuf[threadIdx.x >> 6] = v;
    __syncthreads();
    float r = sbuf[0];
    #pragma unroll
    for (int w = 1; w < 4; w++) r = mode ? fmaxf(r, sbuf[w]) : (r + sbuf[w]);
    return r;
}

// ---------------------------------------------------------------------------
// bf16 MFMA GEMM: C[M,N] = A[M,K] @ Wt[N,K]^T (+bias)(+=Cf)(GELU)
// 128x128 tile, BK=32, 256 thr = 4 waves (2x2 of 64x64), 4x4 MFMA tiles/wave.
// Writes fp32 (Cf) and/or bf16 (Cb) when non-null.
// ---------------------------------------------------------------------------
template <bool BIAS, bool ACCUM, bool GELU>
__global__ __launch_bounds__(256) void gemm_bf16_kernel(
    const unsigned short* __restrict__ A, int lda,
    const unsigned short* __restrict__ Bt, int ldb,
    const float* __restrict__ bias,
    float* __restrict__ Cf, unsigned short* __restrict__ Cb,
    int N, int K)
{
    __shared__ unsigned short As[128 * 40];   // [row][k] pitch 40 (pad 8)
    __shared__ unsigned short Bs[128 * 40];   // [n-row][k]
    const int tid = threadIdx.x;
    const int w = tid >> 6, lane = tid & 63;
    const int l15 = lane & 15, quad = lane >> 4;
    const int m0 = blockIdx.y * 128, n0 = blockIdx.x * 128;
    const int wm = (w >> 1) * 64, wn = (w & 1) * 64;

    float4v acc[4][4];
    #pragma unroll
    for (int i = 0; i < 4; i++)
        #pragma unroll
        for (int j = 0; j < 4; j++) acc[i][j] = (float4v){0.f, 0.f, 0.f, 0.f};

    for (int k0 = 0; k0 < K; k0 += 32) {
        __syncthreads();
        #pragma unroll
        for (int i = 0; i < 2; i++) {
            const int c = tid + i * 256;          // 512 chunks of 16B
            const int row = c >> 2, kc = (c & 3) * 8;
            *(uint4*)(As + row * 40 + kc) =
                *(const uint4*)(A + (size_t)(m0 + row) * lda + k0 + kc);
            *(uint4*)(Bs + row * 40 + kc) =
                *(const uint4*)(Bt + (size_t)(n0 + row) * ldb + k0 + kc);
        }
        __syncthreads();
        short8 Af[4], Bf[4];
        #pragma unroll
        for (int mt = 0; mt < 4; mt++)
            Af[mt] = *(const short8*)(As + (wm + mt * 16 + l15) * 40 + quad * 8);
        #pragma unroll
        for (int nt = 0; nt < 4; nt++)
            Bf[nt] = *(const short8*)(Bs + (wn + nt * 16 + l15) * 40 + quad * 8);
        #pragma unroll
        for (int mt = 0; mt < 4; mt++)
            #pragma unroll
            for (int nt = 0; nt < 4; nt++)
                acc[mt][nt] = __builtin_amdgcn_mfma_f32_16x16x32_bf16(
                    Af[mt], Bf[nt], acc[mt][nt], 0, 0, 0);
    }

    #pragma unroll
    for (int nt = 0; nt < 4; nt++) {
        const int n = n0 + wn + nt * 16 + l15;
        const float bv = BIAS ? bias[n] : 0.f;
        #pragma unroll
        for (int mt = 0; mt < 4; mt++) {
            #pragma unroll
            for (int r = 0; r < 4; r++) {
                const int m = m0 + wm + mt * 16 + quad * 4 + r;
                const size_t off = (size_t)m * N + n;
                float v = acc[mt][nt][r] + bv;
                if (ACCUM) v += Cf[off];
                if (GELU) v = 0.5f * v * (1.f + erff(v * 0.70710678118654752f));
                if (Cf) Cf[off] = v;
                if (Cb) Cb[off] = f2bf(v);
            }
        }
    }
}

// ---------------------------------------------------------------------------
// Weight transpose+cast: W fp32 [K][N] -> Wt bf16 [N][K]
// ---------------------------------------------------------------------------
__global__ __launch_bounds__(256) void wtrans_kernel(
    const float* __restrict__ W, unsigned short* __restrict__ Wt, int K, int N)
{
    __shared__ float t[32][33];
    const int n0 = blockIdx.x * 32, k0 = blockIdx.y * 32;
    const int c = threadIdx.x & 31, r8 = threadIdx.x >> 5;
    #pragma unroll
    for (int i = 0; i < 4; i++) {
        const int r = r8 + i * 8;
        t[r][c] = W[(size_t)(k0 + r) * N + n0 + c];
    }
    __syncthreads();
    #pragma unroll
    for (int i = 0; i < 4; i++) {
        const int r = r8 + i * 8;
        Wt[(size_t)(n0 + r) * K + k0 + c] = f2bf(t[c][r]);
    }
}

// bf16 transpose per batch: in [b][R][C] -> out [b][C][R]
__global__ __launch_bounds__(256) void trans_kernel(
    const unsigned short* __restrict__ v, unsigned short* __restrict__ Vt,
    int R, int C)
{
    __shared__ unsigned short t[32][33];
    const int b = blockIdx.z, r0 = blockIdx.x * 32, c0 = blockIdx.y * 32;
    const int c = threadIdx.x & 31, r8 = threadIdx.x >> 5;
    #pragma unroll
    for (int i = 0; i < 4; i++) {
        const int r = r8 + i * 8;
        t[r][c] = v[((size_t)b * R + r0 + r) * C + c0 + c];
    }
    __syncthreads();
    #pragma unroll
    for (int i = 0; i < 4; i++) {
        const int r = r8 + i * 8;
        Vt[((size_t)b * C + c0 + r) * R + r0 + c] = t[c][r];
    }
}

// fp32 -> bf16 elementwise (count = grid*256*4)
__global__ __launch_bounds__(256) void castbf_kernel(
    const float* __restrict__ x, unsigned short* __restrict__ y)
{
    const size_t i = ((size_t)blockIdx.x * 256 + threadIdx.x) * 4;
    float4 v = *(const float4*)(x + i);
    ushort4 o;
    o.x = f2bf(v.x); o.y = f2bf(v.y); o.z = f2bf(v.z); o.w = f2bf(v.w);
    *(ushort4*)(y + i) = o;
}

// ---------------------------------------------------------------------------
// LayerNorm over 1024 cols; optional residuals; fp32 and/or bf16 outputs.
// ---------------------------------------------------------------------------
DEV void ln_finish(float4 xv, const float* __restrict__ g,
                   const float* __restrict__ bb, float* __restrict__ outf,
                   unsigned short* __restrict__ outb, size_t base)
{
    float s  = xv.x + xv.y + xv.z + xv.w;
    float s2 = xv.x * xv.x + xv.y * xv.y + xv.z * xv.z + xv.w * xv.w;
    #pragma unroll
    for (int off = 32; off; off >>= 1) {
        s += __shfl_xor(s, off);
        s2 += __shfl_xor(s2, off);
    }
    __shared__ float sa[4], sb[4];
    if ((threadIdx.x & 63) == 0) {
        sa[threadIdx.x >> 6] = s; sb[threadIdx.x >> 6] = s2;
    }
    __syncthreads();
    s  = sa[0] + sa[1] + sa[2] + sa[3];
    s2 = sb[0] + sb[1] + sb[2] + sb[3];
    const float mu  = s * (1.f / 1024.f);
    const float var = fmaxf(s2 * (1.f / 1024.f) - mu * mu, 0.f);
    const float inv = rsqrtf(var + 1e-12f);
    const int tid = threadIdx.x;
    float4 gv = ((const float4*)g)[tid];
    float4 bv = ((const float4*)bb)[tid];
    float4 o;
    o.x = (xv.x - mu) * inv * gv.x + bv.x;
    o.y = (xv.y - mu) * inv * gv.y + bv.y;
    o.z = (xv.z - mu) * inv * gv.z + bv.z;
    o.w = (xv.w - mu) * inv * gv.w + bv.w;
    if (outf) ((float4*)(outf + base))[tid] = o;
    if (outb) {
        ushort4 ob;
        ob.x = f2bf(o.x); ob.y = f2bf(o.y); ob.z = f2bf(o.z); ob.w = f2bf(o.w);
        ((ushort4*)(outb + base))[tid] = ob;
    }
}

__global__ __launch_bounds__(256) void ln_kernel(
    const float* __restrict__ x, const float* __restrict__ r1,
    const float* __restrict__ r2, const float* __restrict__ g,
    const float* __restrict__ bb, float* __restrict__ outf,
    unsigned short* __restrict__ outb)
{
    const size_t base = (size_t)blockIdx.x * 1024;
    const int tid = threadIdx.x;
    float4 xv = ((const float4*)(x + base))[tid];
    if (r1) {
        float4 a = ((const float4*)(r1 + base))[tid];
        xv.x += a.x; xv.y += a.y; xv.z += a.z; xv.w += a.w;
    }
    if (r2) {
        float4 a = ((const float4*)(r2 + base))[tid];
        xv.x += a.x; xv.y += a.y; xv.z += a.z; xv.w += a.w;
    }
    ln_finish(xv, g, bb, outf, outb, base);
}

__global__ __launch_bounds__(256) void gate_ln_kernel(
    const float* __restrict__ gpre, const float* __restrict__ co,
    const float* __restrict__ gn, const float* __restrict__ g,
    const float* __restrict__ bb, float* __restrict__ outf,
    unsigned short* __restrict__ outb)
{
    const size_t base = (size_t)blockIdx.x * 1024;
    const int tid = threadIdx.x;
    float4 gp = ((const float4*)(gpre + base))[tid];
    float4 cv = ((const float4*)(co + base))[tid];
    float4 gv = ((const float4*)(gn + base))[tid];
    float4 xv; float s;
    s = 1.f / (1.f + __expf(-gp.x)); xv.x = s * cv.x + (1.f - s) * gv.x;
    s = 1.f / (1.f + __expf(-gp.y)); xv.y = s * cv.y + (1.f - s) * gv.y;
    s = 1.f / (1.f + __expf(-gp.z)); xv.z = s * cv.z + (1.f - s) * gv.z;
    s = 1.f / (1.f + __expf(-gp.w)); xv.w = s * cv.w + (1.f - s) * gv.w;
    ln_finish(xv, g, bb, outf, outb, base);
}

// ---------------------------------------------------------------------------
// MFMA flash attention + inline focal loss, v2.
// Fixed-max softmax (scores bounded; masked -> exp==0), lane-local row sums
// reduced once after the K loop. Q fragments loaded directly from global.
// Block = (n-tile of 64, head, b); wave w owns Q rows [w*16, w*16+16).
// ---------------------------------------------------------------------------
__global__ __launch_bounds__(256) void attn_mfma_kernel(
    const unsigned short* __restrict__ qh,  // [B*N,768] bf16
    const unsigned short* __restrict__ kh,  // [B*N,768]
    const unsigned short* __restrict__ q1,  // [B*N,256]
    const unsigned short* __restrict__ k1,  // [B*N,256]
    const unsigned short* __restrict__ Vt,  // [B*1024(d)][1024(m)] bf16
    const float* __restrict__ am,           // [B*N]
    const float* __restrict__ smask,        // [B,3,N,N]
    unsigned short* __restrict__ ctx,       // [B*N,1024] bf16
    float* __restrict__ nump, float* __restrict__ denp)
{
    const int nb = blockIdx.x;              // n0 = nb*64
    const int h  = blockIdx.y;              // 0 = pos head, 1..3 = struct
    const int b  = blockIdx.z;
    const int tid = threadIdx.x;
    const int w = tid >> 6, lane = tid & 63;
    const int l15 = lane & 15, quad = lane >> 4;
    const int n0 = nb * 64;

    __shared__ unsigned short Ks[32 * 264];     // pitch 264 (pad 8)
    __shared__ unsigned short Vs[256 * 40];     // [d][m] pitch 40
    __shared__ unsigned short Ps[4][16 * 40];   // per-wave P tile

    const unsigned short* qsrc; const unsigned short* ksrc; int kpitch, koff;
    if (h == 0) { qsrc = q1; ksrc = k1; kpitch = 256; koff = 0; }
    else        { qsrc = qh; ksrc = kh; kpitch = 768; koff = (h - 1) * 256; }

    // Q fragments directly from global (each lane: 8 contiguous 16B runs)
    short8 Qf[8];
    {
        const unsigned short* qrow =
            qsrc + (size_t)(b * 1024 + n0 + w * 16 + l15) * kpitch + koff;
        #pragma unroll
        for (int kk = 0; kk < 8; kk++)
            Qf[kk] = *(const short8*)(qrow + kk * 32 + quad * 8);
    }

    float4v O[16];
    #pragma unroll
    for (int i = 0; i < 16; i++) O[i] = (float4v){0.f, 0.f, 0.f, 0.f};
    float lsum[4] = {0.f, 0.f, 0.f, 0.f};
    float flsum = 0.f, dencnt = 0.f;
    const int nrow_base = n0 + w * 16 + quad * 4;  // + r = this lane's rows
    float amn[4];
    #pragma unroll
    for (int r = 0; r < 4; r++) amn[r] = am[b * 1024 + nrow_base + r];
    const float* smbase = (h > 0)
        ? smask + ((size_t)b * 3 + (h - 1)) * 1024 * 1024 : nullptr;

    for (int m0 = 0; m0 < 1024; m0 += 32) {
        __syncthreads();
        for (int c = tid; c < 1024; c += 256) {      // K tile 32x256
            const int row = c >> 5, kc = (c & 31) * 8;
            *(uint4*)(Ks + row * 264 + kc) =
                *(const uint4*)(ksrc + (size_t)(b * 1024 + m0 + row) * kpitch + koff + kc);
        }
        for (int c = tid; c < 1024; c += 256) {      // V tile 256(d) x 32(m)
            const int d = c >> 2, mc = (c & 3) * 8;
            *(uint4*)(Vs + d * 40 + mc) =
                *(const uint4*)(Vt + (size_t)(b * 1024 + h * 256 + d) * 1024 + m0 + mc);
        }
        __syncthreads();

        // S = Q K^T (16 x 32 per wave)
        float4v S[2];
        #pragma unroll
        for (int st = 0; st < 2; st++) {
            float4v a = (float4v){0.f, 0.f, 0.f, 0.f};
            #pragma unroll
            for (int kk = 0; kk < 8; kk++) {
                short8 Kf = *(const short8*)(Ks + (st * 16 + l15) * 264 + kk * 32 + quad * 8);
                a = __builtin_amdgcn_mfma_f32_16x16x32_bf16(Qf[kk], Kf, a, 0, 0, 0);
            }
            S[st] = a;
        }

        // masks, focal loss, exp (fixed-max softmax)
        float e[2][4];
        #pragma unroll
        for (int st = 0; st < 2; st++) {
            const int mcol = m0 + st * 16 + l15;
            const float amm = am[b * 1024 + mcol];
            const float am0 = (1.f - amm) * (-10000.f);
            #pragma unroll
            for (int r = 0; r < 4; r++) {
                const float sraw = S[st][r];
                float scv;
                if (h > 0) {
                    const int nrow = nrow_base + r;
                    const float t  = smbase[(size_t)nrow * 1024 + mcol];
                    const float s3 = sraw + am0;
                    const float idxw =
                        ((amn[r] * amm * ((mcol == nrow) ? 0.f : 1.f)) > 0.5f) ? 1.f : 0.f;
                    // shared-transcendental focal loss:
                    // E=exp(-|s3|); softplus(s3)=max(s3,0)+log(1+E);
                    // p=sigmoid(s3)=(s3>=0 ? 1 : E)/(1+E);
                    // -log_sigmoid(s3)=softplus(-s3)=softplus(s3)-s3
                    const float E = __expf(-fabsf(s3));
                    const float L = __logf(1.f + E);
                    const float R = 1.f / (1.f + E);
                    const float p = (s3 >= 0.f) ? R : E * R;
                    const float sp = fmaxf(s3, 0.f) + L;      // softplus(s3)
                    const float omp = 1.f - p;
                    flsum += idxw * (0.25f * t * omp * omp * (sp - s3)
                                   + 0.75f * (1.f - t) * p * p * sp);
                    dencnt += idxw;
                    scv = sraw * 0.0625f + (1.f - t) * (-10000.f);
                } else {
                    scv = sraw * 0.0625f + am0;
                }
                const float ev = __expf(fminf(scv, 30.f));  // clamp: overflow guard
                e[st][r] = ev;
                lsum[r] += ev;
            }
        }

        // P: C-layout -> LDS -> A-layout (per-wave buffer; no barrier needed)
        #pragma unroll
        for (int st = 0; st < 2; st++)
            #pragma unroll
            for (int r = 0; r < 4; r++)
                Ps[w][(quad * 4 + r) * 40 + st * 16 + l15] = f2bf(e[st][r]);
        const short8 Pf = *(const short8*)(&Ps[w][l15 * 40 + quad * 8]);
        #pragma unroll
        for (int dt = 0; dt < 16; dt++) {
            short8 Vf = *(const short8*)(Vs + (dt * 16 + l15) * 40 + quad * 8);
            O[dt] = __builtin_amdgcn_mfma_f32_16x16x32_bf16(Pf, Vf, O[dt], 0, 0, 0);
        }
    }

    // one row-sum reduction across the 16 col-lanes, then write out
    float rinv[4];
    #pragma unroll
    for (int r = 0; r < 4; r++) {
        float s = lsum[r];
        #pragma unroll
        for (int off = 8; off; off >>= 1) s += __shfl_xor(s, off);
        rinv[r] = 1.f / s;
    }
    #pragma unroll
    for (int dt = 0; dt < 16; dt++)
        #pragma unroll
        for (int r = 0; r < 4; r++)
            ctx[(size_t)(b * 1024 + nrow_base + r) * 1024 + h * 256 + dt * 16 + l15]
                = f2bf(O[dt][r] * rinv[r]);

    if (h > 0) {
        const float fb = block_reduce(flsum, 0);
        if (tid == 0) nump[(b * 3 + (h - 1)) * 16 + nb] = fb;
        if (h == 1) {
            const float db = block_reduce(dencnt, 0);
            if (tid == 0) denp[b * 16 + nb] = db;
        }
    }
}

// ---------------------------------------------------------------------------
// MFMA cross attention v2 (fixed-max softmax, direct Q loads).
// Block = (n-tile of 64, head, b). qk-dim 64, v-dim 256, M = 512 keys.
// ---------------------------------------------------------------------------
__global__ __launch_bounds__(256) void cross_mfma_kernel(
    const unsigned short* __restrict__ cq,   // [B*N, 256] bf16 (4 heads x 64)
    const unsigned short* __restrict__ ck,   // [B*512, 256] bf16
    const unsigned short* __restrict__ cvt,  // [B][1024(d)][512(m)] bf16
    const float* __restrict__ csm,           // [B*1024, 512]
    unsigned short* __restrict__ cctx)       // [B*N, 1024] bf16
{
    const int nb = blockIdx.x;               // 16 tiles of 64 q-rows
    const int h  = blockIdx.y;               // 4 heads
    const int b  = blockIdx.z;
    const int tid = threadIdx.x;
    const int w = tid >> 6, lane = tid & 63;
    const int l15 = lane & 15, quad = lane >> 4;
    const int n0 = nb * 64;

    __shared__ unsigned short Ks[32 * 72];
    __shared__ unsigned short Vs[256 * 40];   // [d][m] pitch 40
    __shared__ unsigned short Ps[4][16 * 40];

    short8 Qf[2];
    {
        const unsigned short* qrow =
            cq + (size_t)(b * 1024 + n0 + w * 16 + l15) * 256 + h * 64;
        #pragma unroll
        for (int kk = 0; kk < 2; kk++)
            Qf[kk] = *(const short8*)(qrow + kk * 32 + quad * 8);
    }

    float4v O[16];
    #pragma unroll
    for (int i = 0; i < 16; i++) O[i] = (float4v){0.f, 0.f, 0.f, 0.f};
    float lsum[4] = {0.f, 0.f, 0.f, 0.f};
    const int nrow_base = n0 + w * 16 + quad * 4;

    for (int m0 = 0; m0 < 512; m0 += 32) {
        __syncthreads();
        if (tid < 256) {                         // K tile 32 x 64
            const int row = tid >> 3, kc = (tid & 7) * 8;
            *(uint4*)(Ks + row * 72 + kc) =
                *(const uint4*)(ck + (size_t)(b * 512 + m0 + row) * 256 + h * 64 + kc);
        }
        for (int c = tid; c < 1024; c += 256) {  // V tile 256(d) x 32(m)
            const int d = c >> 2, mc = (c & 3) * 8;
            *(uint4*)(Vs + d * 40 + mc) =
                *(const uint4*)(cvt + (size_t)(b * 1024 + h * 256 + d) * 512 + m0 + mc);
        }
        __syncthreads();

        // S = Q K^T, masked exp
        float e[2][4];
        #pragma unroll
        for (int st = 0; st < 2; st++) {
            float4v a = (float4v){0.f, 0.f, 0.f, 0.f};
            #pragma unroll
            for (int kk = 0; kk < 2; kk++) {
                short8 Kf = *(const short8*)(Ks + (st * 16 + l15) * 72 + kk * 32 + quad * 8);
                a = __builtin_amdgcn_mfma_f32_16x16x32_bf16(Qf[kk], Kf, a, 0, 0, 0);
            }
            const int mcol = m0 + st * 16 + l15;
            #pragma unroll
            for (int r = 0; r < 4; r++) {
                const float msk = csm[(size_t)(b * 1024 + nrow_base + r) * 512 + mcol];
                const float scv = a[r] * 0.125f + (1.f - msk) * (-10000.f);
                const float ev = __expf(fminf(scv, 30.f));
                e[st][r] = ev;
                lsum[r] += ev;
            }
        }

        // P: C-layout -> LDS -> A-layout (per-wave; no barrier)
        #pragma unroll
        for (int st = 0; st < 2; st++)
            #pragma unroll
            for (int r = 0; r < 4; r++)
                Ps[w][(quad * 4 + r) * 40 + st * 16 + l15] = f2bf(e[st][r]);
        const short8 Pf = *(const short8*)(&Ps[w][l15 * 40 + quad * 8]);
        #pragma unroll
        for (int dt = 0; dt < 16; dt++) {
            short8 Vf = *(const short8*)(Vs + (dt * 16 + l15) * 40 + quad * 8);
            O[dt] = __builtin_amdgcn_mfma_f32_16x16x32_bf16(Pf, Vf, O[dt], 0, 0, 0);
        }
    }

    float rinv[4];
    #pragma unroll
    for (int r = 0; r < 4; r++) {
        float s = lsum[r];
        #pragma unroll
        for (int off = 8; off; off >>= 1) s += __shfl_xor(s, off);
        rinv[r] = 1.f / s;
    }
    #pragma unroll
    for (int dt = 0; dt < 16; dt++)
        #pragma unroll
        for (int r = 0; r < 4; r++)
            cctx[(size_t)(b * 1024 + nrow_base + r) * 1024 + h * 256 + dt * 16 + l15]
                = f2bf(O[dt][r] * rinv[r]);
}

// loss = sum(nump[384]) / (3 * sum(denp[128])), deterministic
__global__ __launch_bounds__(256) void loss_reduce_kernel(
    const float* __restrict__ nump, const float* __restrict__ denp,
    float* __restrict__ out)
{
    __shared__ double sn[256], sd[256];
    const int tid = threadIdx.x;
    double ns = 0.0, ds = 0.0;
    for (int i = tid; i < 384; i += 256) ns += (double)nump[i];
    for (int i = tid; i < 128; i += 256) ds += (double)denp[i];
    sn[tid] = ns; sd[tid] = ds;
    __syncthreads();
    for (int off = 128; off; off >>= 1) {
        if (tid < off) { sn[tid] += sn[tid + off]; sd[tid] += sd[tid + off]; }
        __syncthreads();
    }
    if (tid == 0) out[0] = (float)(sn[0] / (3.0 * sd[0]));
}

// ---------------------------------------------------------------------------
extern "C" void kernel_launch(void* const* d_in, const int* in_sizes, int n_in,
                              void* d_out, int out_size, void* d_ws, size_t ws_size,
                              hipStream_t stream)
{
    (void)in_sizes; (void)n_in; (void)out_size; (void)ws_size;
    const float* hs   = (const float*)d_in[0];
    const float* am   = (const float*)d_in[1];
    const float* smask= (const float*)d_in[2];
    const float* sent = (const float*)d_in[3];
    const float* ent  = (const float*)d_in[4];
    const float* csm  = (const float*)d_in[5];
    const float* enc  = (const float*)d_in[6];
    const float* Wq  = (const float*)d_in[8];  const float* bq  = (const float*)d_in[9];
    const float* Wk  = (const float*)d_in[10]; const float* bk  = (const float*)d_in[11];
    const float* Wv  = (const float*)d_in[12]; const float* bv  = (const float*)d_in[13];
    const float* Wq1 = (const float*)d_in[14]; const float* bq1 = (const float*)d_in[15];
    const float* Wk1 = (const float*)d_in[16]; const float* bk1 = (const float*)d_in[17];
    const float* ln_g= (const float*)d_in[18]; const float* ln_b= (const float*)d_in[19];
    const float* gW  = (const float*)d_in[20]; const float* gb  = (const float*)d_in[21];
    const float* gng = (const float*)d_in[22]; const float* gnb = (const float*)d_in[23];
    const float* cWq = (const float*)d_in[24]; const float* cbq = (const float*)d_in[25];
    const float* cWk = (const float*)d_in[26]; const float* cbk = (const float*)d_in[27];
    const float* cWv = (const float*)d_in[28]; const float* cbv = (const float*)d_in[29];
    const float* cWo = (const float*)d_in[30]; const float* cbo = (const float*)d_in[31];
    const float* cWg = (const float*)d_in[32]; const float* cbg = (const float*)d_in[33];
    const float* clg = (const float*)d_in[34]; const float* clb = (const float*)d_in[35];
    const float* oW1 = (const float*)d_in[36]; const float* ob1 = (const float*)d_in[37];
    const float* l1g = (const float*)d_in[38]; const float* l1b = (const float*)d_in[39];
    const float* oW2 = (const float*)d_in[40]; const float* ob2 = (const float*)d_in[41];
    const float* oW3 = (const float*)d_in[42]; const float* ob3 = (const float*)d_in[43];
    const float* l3g = (const float*)d_in[44]; const float* l3b = (const float*)d_in[45];
    float* out = (float*)d_out;

    typedef unsigned short ush;
    char* wsb = (char*)d_ws;
    // ---- weight-transpose arena (bf16), 14,155,776 elements ----
    ush* WT   = (ush*)wsb;
    ush* wqT  = WT;             ush* wkT  = WT + 786432;   ush* wvT  = WT + 1572864;
    ush* wq1T = WT + 2621440;   ush* wk1T = WT + 2883584;  ush* gWT_ = WT + 3145728;
    ush* cWqT = WT + 4194304;   ush* cWkT = WT + 4456448;  ush* cWvT = WT + 4718592;
    ush* cWoT = WT + 5767168;   ush* cWgT = WT + 6815744;  ush* oW1T = WT + 8912896;
    ush* oW2T = WT + 9961472;   ush* oW3T = WT + 12058624;
    // ---- activation slabs (byte offsets; lifetimes reused) ----
    ush*  hs_bf   = (ush*)(wsb + 28311552);
    ush*  enc_bf  = (ush*)(wsb + 45088768);
    ush*  q_bf    = (ush*)(wsb + 53477376);
    ush*  k_bf    = (ush*)(wsb + 66060288);
    ush*  v_bf    = (ush*)(wsb + 78643200);
    ush*  Vt      = (ush*)(wsb + 95420416);
    ush*  h1_bf   = (ush*)(wsb + 112197632);
    ush*  q1_bf   = (ush*)(wsb + 128974848);
    ush*  k1_bf   = (ush*)(wsb + 133169152);
    ush*  ctx_bf  = (ush*)(wsb + 137363456);
    float* nump   = (float*)(wsb + 154140672);
    float* denp   = (float*)(wsb + 154142208);
    float* gnn_f  = (float*)(wsb + 154144768);
    float* gnnout_f = (float*)(wsb + 187699200);
    ush*  gnnout_b  = (ush*)(wsb + 221253632);
    // reuse (strictly ordered lifetimes):
    ush*  cq_b      = (ush*)(wsb + 53477376);     // over q_bf
    ush*  ck_b      = (ush*)(wsb + 66060288);     // over k_bf
    ush*  cv_b      = (ush*)(wsb + 78643200);     // over v_bf
    ush*  cctx_b    = (ush*)(wsb + 95420416);     // over Vt
    ush*  cvt       = (ush*)(wsb + 238030848);    // after gnnout_b
    float* cctxo_f  = (float*)(wsb + 154144768);  // over gnn_f
    ush*  cctxo_b   = (ush*)(wsb + 28311552);     // over hs_bf
    float* gatepre_f= (float*)(wsb + 112197632);  // over h1/q1/k1/ctx
    ush*  crossout_b= (ush*)(wsb + 221253632);    // over gnnout_b
    float* t_f      = (float*)(wsb + 154144768);  // over cctxo_f
    float* h_f      = (float*)(wsb + 187699200);  // over gnnout_f
    ush*  h_b       = (ush*)(wsb + 28311552);     // over cctxo_b
    ush*  h2g_b     = (ush*)(wsb + 45088768);     // over enc/q/k region
    float* h3_f     = (float*)(wsb + 154144768);  // over t_f

    dim3 blk(256);
    // ---- phase 0: casts + weight transposes ----
    castbf_kernel<<<8192, blk, 0, stream>>>(hs, hs_bf);
    castbf_kernel<<<4096, blk, 0, stream>>>(enc, enc_bf);
    wtrans_kernel<<<dim3(768/32, 1024/32), blk, 0, stream>>>(Wq, wqT, 1024, 768);
    wtrans_kernel<<<dim3(768/32, 1024/32), blk, 0, stream>>>(Wk, wkT, 1024, 768);
    wtrans_kernel<<<dim3(32, 32), blk, 0, stream>>>(Wv, wvT, 1024, 1024);
    wtrans_kernel<<<dim3(8, 32), blk, 0, stream>>>(Wq1, wq1T, 1024, 256);
    wtrans_kernel<<<dim3(8, 32), blk, 0, stream>>>(Wk1, wk1T, 1024, 256);
    wtrans_kernel<<<dim3(32, 32), blk, 0, stream>>>(gW, gWT_, 1024, 1024);
    wtrans_kernel<<<dim3(8, 32), blk, 0, stream>>>(cWq, cWqT, 1024, 256);
    wtrans_kernel<<<dim3(8, 32), blk, 0, stream>>>(cWk, cWkT, 1024, 256);
    wtrans_kernel<<<dim3(32, 32), blk, 0, stream>>>(cWv, cWvT, 1024, 1024);
    wtrans_kernel<<<dim3(32, 32), blk, 0, stream>>>(cWo, cWoT, 1024, 1024);
    wtrans_kernel<<<dim3(32, 64), blk, 0, stream>>>(cWg, cWgT, 2048, 1024);
    wtrans_kernel<<<dim3(32, 32), blk, 0, stream>>>(oW1, oW1T, 1024, 1024);
    wtrans_kernel<<<dim3(64, 32), blk, 0, stream>>>(oW2, oW2T, 1024, 2048);
    wtrans_kernel<<<dim3(32, 64), blk, 0, stream>>>(oW3, oW3T, 2048, 1024);
    // ---- phase 1: projections ----
    gemm_bf16_kernel<true,false,false><<<dim3(6, 64), blk, 0, stream>>>(
        hs_bf, 1024, wqT, 1024, bq, nullptr, q_bf, 768, 1024);
    gemm_bf16_kernel<true,false,false><<<dim3(6, 64), blk, 0, stream>>>(
        hs_bf, 1024, wkT, 1024, bk, nullptr, k_bf, 768, 1024);
    gemm_bf16_kernel<true,false,false><<<dim3(8, 64), blk, 0, stream>>>(
        hs_bf, 1024, wvT, 1024, bv, nullptr, v_bf, 1024, 1024);
    ln_kernel<<<8192, blk, 0, stream>>>(hs, sent, ent, ln_g, ln_b, nullptr, h1_bf);
    gemm_bf16_kernel<true,false,false><<<dim3(2, 64), blk, 0, stream>>>(
        h1_bf, 1024, wq1T, 1024, bq1, nullptr, q1_bf, 256, 1024);
    gemm_bf16_kernel<true,false,false><<<dim3(2, 64), blk, 0, stream>>>(
        h1_bf, 1024, wk1T, 1024, bk1, nullptr, k1_bf, 256, 1024);
    trans_kernel<<<dim3(32, 32, 8), blk, 0, stream>>>(v_bf, Vt, 1024, 1024);
    // ---- phase 2: attention + loss ----
    attn_mfma_kernel<<<dim3(16, 4, 8), blk, 0, stream>>>(
        q_bf, k_bf, q1_bf, k1_bf, Vt, am, smask, ctx_bf, nump, denp);
    loss_reduce_kernel<<<1, blk, 0, stream>>>(nump, denp, out + 8388608);
    // ---- phase 3: gnn ----
    gemm_bf16_kernel<true,false,false><<<dim3(8, 64), blk, 0, stream>>>(
        ctx_bf, 1024, gWT_, 1024, gb, gnn_f, nullptr, 1024, 1024);
    ln_kernel<<<8192, blk, 0, stream>>>(gnn_f, nullptr, nullptr, gng, gnb,
                                        gnnout_f, gnnout_b);
    // ---- phase 4: cross attention + gate ----
    gemm_bf16_kernel<true,false,false><<<dim3(2, 64), blk, 0, stream>>>(
        gnnout_b, 1024, cWqT, 1024, cbq, nullptr, cq_b, 256, 1024);
    gemm_bf16_kernel<true,false,false><<<dim3(2, 32), blk, 0, stream>>>(
        enc_bf, 1024, cWkT, 1024, cbk, nullptr, ck_b, 256, 1024);
    gemm_bf16_kernel<true,false,false><<<dim3(8, 32), blk, 0, stream>>>(
        enc_bf, 1024, cWvT, 1024, cbv, nullptr, cv_b, 1024, 1024);
    trans_kernel<<<dim3(16, 32, 8), blk, 0, stream>>>(cv_b, cvt, 512, 1024);
    cross_mfma_kernel<<<dim3(16, 4, 8), blk, 0, stream>>>(
        cq_b, ck_b, cvt, csm, cctx_b);
    gemm_bf16_kernel<true,false,false><<<dim3(8, 64), blk, 0, stream>>>(
        cctx_b, 1024, cWoT, 1024, cbo, cctxo_f, cctxo_b, 1024, 1024);
    gemm_bf16_kernel<true,false,false><<<dim3(8, 64), blk, 0, stream>>>(
        gnnout_b, 1024, cWgT, 2048, cbg, gatepre_f, nullptr, 1024, 1024);
    gemm_bf16_kernel<false,true,false><<<dim3(8, 64), blk, 0, stream>>>(
        cctxo_b, 1024, cWgT + 1024, 2048, nullptr, gatepre_f, nullptr, 1024, 1024);
    gate_ln_kernel<<<8192, blk, 0, stream>>>(gatepre_f, cctxo_f, gnnout_f,
                                             clg, clb, nullptr, crossout_b);
    // ---- phase 5: output block ----
    gemm_bf16_kernel<true,false,false><<<dim3(8, 64), blk, 0, stream>>>(
        crossout_b, 1024, oW1T, 1024, ob1, t_f, nullptr, 1024, 1024);
    ln_kernel<<<8192, blk, 0, stream>>>(t_f, hs, nullptr, l1g, l1b, h_f, h_b);
    gemm_bf16_kernel<true,false,true><<<dim3(16, 64), blk, 0, stream>>>(
        h_b, 1024, oW2T, 1024, ob2, nullptr, h2g_b, 2048, 1024);
    gemm_bf16_kernel<true,false,false><<<dim3(8, 64), blk, 0, stream>>>(
        h2g_b, 2048, oW3T, 2048, ob3, h3_f, nullptr, 1024, 2048);
    ln_kernel<<<8192, blk, 0, stream>>>(h3_f, h_f, nullptr, l3g, l3b, out, nullptr);
}